// Round 1
// baseline (789.270 us; speedup 1.0000x reference)
//
#include <hip/hip_runtime.h>
#include <math.h>

// Problem constants (fixed by the reference)
#define B_   4
#define N_   2048
#define DIM_ 512
#define T_   16
#define H_   8
#define DH_  64
// num_patches = N/T = 128; 64-wide tiles align inside patches -> decay scalar per tile pair

// ---------------------------------------------------------------------------
// Kernel 1: per-row LayerNorm stats (mu, rstd). One wave per row.
// ---------------------------------------------------------------------------
__global__ __launch_bounds__(256) void ln_stats_kernel(const float* __restrict__ x,
                                                       float* __restrict__ stats) {
  int row  = blockIdx.x * 4 + (threadIdx.x >> 6);
  int lane = threadIdx.x & 63;
  const float4* xr = (const float4*)(x + (size_t)row * DIM_);
  float4 v0 = xr[lane * 2 + 0];
  float4 v1 = xr[lane * 2 + 1];
  float s  = v0.x + v0.y + v0.z + v0.w + v1.x + v1.y + v1.z + v1.w;
  float ss = v0.x*v0.x + v0.y*v0.y + v0.z*v0.z + v0.w*v0.w
           + v1.x*v1.x + v1.y*v1.y + v1.z*v1.z + v1.w*v1.w;
#pragma unroll
  for (int off = 32; off > 0; off >>= 1) {
    s  += __shfl_xor(s, off);
    ss += __shfl_xor(ss, off);
  }
  if (lane == 0) {
    float mu  = s * (1.0f / DIM_);
    float var = ss * (1.0f / DIM_) - mu * mu;
    stats[2 * row + 0] = mu;
    stats[2 * row + 1] = rsqrtf(var + 1e-5f);
  }
}

// ---------------------------------------------------------------------------
// Kernel 2: qkv = LN(x) @ W_qkv, output scattered into q/k/v [B,H,N,DH].
// 128x128 tile, K-step 16, 256 threads, 8x8 per thread (split 4+4 halves).
// ---------------------------------------------------------------------------
__global__ __launch_bounds__(256) void qkv_gemm_kernel(
    const float* __restrict__ x, const float* __restrict__ stats,
    const float* __restrict__ gamma, const float* __restrict__ beta,
    const float* __restrict__ Wqkv,
    float* __restrict__ qo, float* __restrict__ ko, float* __restrict__ vo) {
  __shared__ float At[16][132];  // [k][row], stride 132 keeps f4 reads 16B-aligned
  __shared__ float Bs[16][132];  // [k][col]
  int tid = threadIdx.x;
  int tx = tid & 15, ty = tid >> 4;
  int col0 = blockIdx.x * 128;
  int row0 = blockIdx.y * 128;
  float acc[8][8] = {};

  for (int k0 = 0; k0 < DIM_; k0 += 16) {
    // A tile: 128 rows x 16 k, LN applied inline
#pragma unroll
    for (int it = 0; it < 2; ++it) {
      int f = tid + it * 256;          // float4 index in [0,512)
      int r = f >> 2;
      int kc = (f & 3) << 2;
      int grow = row0 + r;
      float4 xv = *(const float4*)&x[(size_t)grow * DIM_ + k0 + kc];
      float mu = stats[2 * grow], rstd = stats[2 * grow + 1];
      At[kc + 0][r] = (xv.x - mu) * rstd * gamma[k0 + kc + 0] + beta[k0 + kc + 0];
      At[kc + 1][r] = (xv.y - mu) * rstd * gamma[k0 + kc + 1] + beta[k0 + kc + 1];
      At[kc + 2][r] = (xv.z - mu) * rstd * gamma[k0 + kc + 2] + beta[k0 + kc + 2];
      At[kc + 3][r] = (xv.w - mu) * rstd * gamma[k0 + kc + 3] + beta[k0 + kc + 3];
    }
    // B tile: 16 k x 128 cols (W_qkv row-major [512][1536])
#pragma unroll
    for (int it = 0; it < 2; ++it) {
      int f = tid + it * 256;
      int kr = f >> 5;
      int cc = (f & 31) << 2;
      *(float4*)&Bs[kr][cc] = *(const float4*)&Wqkv[(size_t)(k0 + kr) * 1536 + col0 + cc];
    }
    __syncthreads();
#pragma unroll
    for (int kk = 0; kk < 16; ++kk) {
      float4 a0 = *(float4*)&At[kk][ty * 4];
      float4 a1 = *(float4*)&At[kk][64 + ty * 4];
      float4 b0 = *(float4*)&Bs[kk][tx * 4];
      float4 b1 = *(float4*)&Bs[kk][64 + tx * 4];
      float avv[8] = {a0.x, a0.y, a0.z, a0.w, a1.x, a1.y, a1.z, a1.w};
      float bvv[8] = {b0.x, b0.y, b0.z, b0.w, b1.x, b1.y, b1.z, b1.w};
#pragma unroll
      for (int i = 0; i < 8; ++i)
#pragma unroll
        for (int j = 0; j < 8; ++j)
          acc[i][j] = fmaf(avv[i], bvv[j], acc[i][j]);
    }
    __syncthreads();
  }

  // scatter to q/k/v [B][H][N][DH]
#pragma unroll
  for (int ih = 0; ih < 2; ++ih) {
#pragma unroll
    for (int i = 0; i < 4; ++i) {
      int grow = row0 + ih * 64 + ty * 4 + i;
      int bb = grow >> 11;       // /2048
      int n  = grow & 2047;
#pragma unroll
      for (int jh = 0; jh < 2; ++jh) {
        int gcol = col0 + jh * 64 + tx * 4;
        int part = gcol >> 9;    // /512 -> 0:q 1:k 2:v
        int rem  = gcol & 511;
        int h = rem >> 6, d = rem & 63;
        float* dst = (part == 0) ? qo : ((part == 1) ? ko : vo);
        float4 o;
        o.x = acc[ih * 4 + i][jh * 4 + 0];
        o.y = acc[ih * 4 + i][jh * 4 + 1];
        o.z = acc[ih * 4 + i][jh * 4 + 2];
        o.w = acc[ih * 4 + i][jh * 4 + 3];
        *(float4*)&dst[(((size_t)bb * H_ + h) * N_ + n) * DH_ + d] = o;
      }
    }
  }
}

// ---------------------------------------------------------------------------
// Kernel 3: time-decay attention, flash-style without max-subtraction
// (logits = relu(qk)*decay are in [0, ~2] -> exp cannot overflow).
// Block: 64 queries x one (b,h); loop over 32 K-tiles of 64 keys.
// Decay is a single scalar per (q-tile, k-tile): tiles align within patches.
// ---------------------------------------------------------------------------
__global__ __launch_bounds__(256) void attn_kernel(
    const float* __restrict__ q, const float* __restrict__ k,
    const float* __restrict__ v, const float* __restrict__ R,
    const float* __restrict__ a, const float* __restrict__ c,
    float* __restrict__ aout) {
  __shared__ float Qt[64][68];   // [d][row], scale folded in
  __shared__ float KP[64][68];   // K-tile transposed [d][m]; reused as P^T [m][q]
  __shared__ float Vs[64][68];   // [m][d]
  int tid = threadIdx.x;
  int tx = tid & 15, ty = tid >> 4;
  int qt = blockIdx.x;           // 0..31 query tile
  int bh = blockIdx.y;           // 0..31 = b*H+h
  int b = bh >> 3, h = bh & 7;
  float aab = fabsf(a[h]);
  float cab = fabsf(c[h]);
  const float* qp = q + ((size_t)bh * N_ + qt * 64) * DH_;
  const float* kp = k + (size_t)bh * N_ * DH_;
  const float* vp = v + (size_t)bh * N_ * DH_;

  // load Q tile transposed, fold in scale = DH^-0.5 = 0.125
#pragma unroll
  for (int it = 0; it < 4; ++it) {
    int f = tid + it * 256;
    int r = f >> 4;
    int d4 = (f & 15) << 2;
    float4 qv = *(const float4*)&qp[r * DH_ + d4];
    Qt[d4 + 0][r] = qv.x * 0.125f;
    Qt[d4 + 1][r] = qv.y * 0.125f;
    Qt[d4 + 2][r] = qv.z * 0.125f;
    Qt[d4 + 3][r] = qv.w * 0.125f;
  }

  float o[4][4] = {};
  float rsum[4] = {};
  int ti = qt >> 1;

  for (int kt = 0; kt < 32; ++kt) {
    // load K (transposed) + V tiles
#pragma unroll
    for (int it = 0; it < 4; ++it) {
      int f = tid + it * 256;
      int r = f >> 4;
      int d4 = (f & 15) << 2;
      float4 kv = *(const float4*)&kp[(size_t)(kt * 64 + r) * DH_ + d4];
      KP[d4 + 0][r] = kv.x;
      KP[d4 + 1][r] = kv.y;
      KP[d4 + 2][r] = kv.z;
      KP[d4 + 3][r] = kv.w;
      *(float4*)&Vs[r][d4] = *(const float4*)&vp[(size_t)(kt * 64 + r) * DH_ + d4];
    }
    __syncthreads();  // covers Qt on iter 0 too

    int tj = kt >> 1;
    float Rv = R[b * (T_ * T_) + ti * T_ + tj];
    float dec = 1.0f / (1.0f + __expf(aab * Rv - cab));

    // S = Qt^T KP : 4x4 per thread
    float s[4][4] = {};
#pragma unroll 8
    for (int kk = 0; kk < 64; ++kk) {
      float4 qv = *(float4*)&Qt[kk][ty * 4];
      float4 kv = *(float4*)&KP[kk][tx * 4];
      float qa[4] = {qv.x, qv.y, qv.z, qv.w};
      float ka[4] = {kv.x, kv.y, kv.z, kv.w};
#pragma unroll
      for (int i = 0; i < 4; ++i)
#pragma unroll
        for (int j = 0; j < 4; ++j)
          s[i][j] = fmaf(qa[i], ka[j], s[i][j]);
    }
    __syncthreads();  // everyone done reading KP before P^T overwrites it

    float p[4][4];
#pragma unroll
    for (int i = 0; i < 4; ++i)
#pragma unroll
      for (int j = 0; j < 4; ++j) {
        float l = fmaxf(s[i][j], 0.0f) * dec;
        p[i][j] = __expf(l);
        rsum[i] += p[i][j];
      }
    // store P^T[m][q]
#pragma unroll
    for (int j = 0; j < 4; ++j) {
      float4 pv;
      pv.x = p[0][j]; pv.y = p[1][j]; pv.z = p[2][j]; pv.w = p[3][j];
      *(float4*)&KP[tx * 4 + j][ty * 4] = pv;
    }
    __syncthreads();

    // O += P @ V : 4q x 4d per thread
#pragma unroll 8
    for (int m = 0; m < 64; ++m) {
      float4 pv = *(float4*)&KP[m][ty * 4];
      float4 vv = *(float4*)&Vs[m][tx * 4];
      float pa[4] = {pv.x, pv.y, pv.z, pv.w};
      float va[4] = {vv.x, vv.y, vv.z, vv.w};
#pragma unroll
      for (int i = 0; i < 4; ++i)
#pragma unroll
        for (int j = 0; j < 4; ++j)
          o[i][j] = fmaf(pa[i], va[j], o[i][j]);
    }
    __syncthreads();  // before next tile overwrites KP/Vs
  }

  // reduce row sums across the 16 tx lanes (same wave)
#pragma unroll
  for (int off = 1; off < 16; off <<= 1)
#pragma unroll
    for (int i = 0; i < 4; ++i)
      rsum[i] += __shfl_xor(rsum[i], off);

  // normalize + write attn_out [B][N][H*DH] (h-major cols, ready for out proj)
#pragma unroll
  for (int i = 0; i < 4; ++i) {
    float inv = 1.0f / rsum[i];
    int n = qt * 64 + ty * 4 + i;
    float4 ov;
    ov.x = o[i][0] * inv; ov.y = o[i][1] * inv;
    ov.z = o[i][2] * inv; ov.w = o[i][3] * inv;
    *(float4*)&aout[((size_t)b * N_ + n) * (H_ * DH_) + h * DH_ + tx * 4] = ov;
  }
}

// ---------------------------------------------------------------------------
// Kernel 4: out = attn_out @ W_out. Same 128x128 tiling as kernel 2, no LN.
// ---------------------------------------------------------------------------
__global__ __launch_bounds__(256) void out_gemm_kernel(
    const float* __restrict__ A, const float* __restrict__ Wout,
    float* __restrict__ out) {
  __shared__ float At[16][132];
  __shared__ float Bs[16][132];
  int tid = threadIdx.x;
  int tx = tid & 15, ty = tid >> 4;
  int col0 = blockIdx.x * 128;
  int row0 = blockIdx.y * 128;
  float acc[8][8] = {};

  for (int k0 = 0; k0 < 512; k0 += 16) {
#pragma unroll
    for (int it = 0; it < 2; ++it) {
      int f = tid + it * 256;
      int r = f >> 2;
      int kc = (f & 3) << 2;
      int grow = row0 + r;
      float4 xv = *(const float4*)&A[(size_t)grow * 512 + k0 + kc];
      At[kc + 0][r] = xv.x;
      At[kc + 1][r] = xv.y;
      At[kc + 2][r] = xv.z;
      At[kc + 3][r] = xv.w;
    }
#pragma unroll
    for (int it = 0; it < 2; ++it) {
      int f = tid + it * 256;
      int kr = f >> 5;
      int cc = (f & 31) << 2;
      *(float4*)&Bs[kr][cc] = *(const float4*)&Wout[(size_t)(k0 + kr) * 512 + col0 + cc];
    }
    __syncthreads();
#pragma unroll
    for (int kk = 0; kk < 16; ++kk) {
      float4 a0 = *(float4*)&At[kk][ty * 4];
      float4 a1 = *(float4*)&At[kk][64 + ty * 4];
      float4 b0 = *(float4*)&Bs[kk][tx * 4];
      float4 b1 = *(float4*)&Bs[kk][64 + tx * 4];
      float avv[8] = {a0.x, a0.y, a0.z, a0.w, a1.x, a1.y, a1.z, a1.w};
      float bvv[8] = {b0.x, b0.y, b0.z, b0.w, b1.x, b1.y, b1.z, b1.w};
#pragma unroll
      for (int i = 0; i < 8; ++i)
#pragma unroll
        for (int j = 0; j < 8; ++j)
          acc[i][j] = fmaf(avv[i], bvv[j], acc[i][j]);
    }
    __syncthreads();
  }

#pragma unroll
  for (int ih = 0; ih < 2; ++ih) {
#pragma unroll
    for (int i = 0; i < 4; ++i) {
      int grow = row0 + ih * 64 + ty * 4 + i;
#pragma unroll
      for (int jh = 0; jh < 2; ++jh) {
        int gcol = col0 + jh * 64 + tx * 4;
        float4 o;
        o.x = acc[ih * 4 + i][jh * 4 + 0];
        o.y = acc[ih * 4 + i][jh * 4 + 1];
        o.z = acc[ih * 4 + i][jh * 4 + 2];
        o.w = acc[ih * 4 + i][jh * 4 + 3];
        *(float4*)&out[(size_t)grow * 512 + gcol] = o;
      }
    }
  }
}

// ---------------------------------------------------------------------------
extern "C" void kernel_launch(void* const* d_in, const int* in_sizes, int n_in,
                              void* d_out, int out_size, void* d_ws, size_t ws_size,
                              hipStream_t stream) {
  (void)in_sizes; (void)n_in;
  const float* x     = (const float*)d_in[0];
  const float* R     = (const float*)d_in[1];
  const float* gamma = (const float*)d_in[2];
  const float* beta  = (const float*)d_in[3];
  const float* Wqkv  = (const float*)d_in[4];
  const float* Wout  = (const float*)d_in[5];
  const float* av    = (const float*)d_in[6];
  const float* cv    = (const float*)d_in[7];
  float* out = (float*)d_out;
  float* ws  = (float*)d_ws;

  const size_t rows   = (size_t)B_ * N_;    // 8192
  const size_t statsN = rows * 2;           // 16384 floats
  const size_t tenN   = rows * DIM_;        // 4194304 floats per tensor

  float* stats = ws;
  float* qws = stats + statsN;
  float* kws = qws + tenN;
  float* vws = kws + tenN;

  // plan A: attn-out lives in ws; plan B (small ws): route through d_out,
  // final gemm into (dead) q buffer, then d2d copy back. Branch is on a
  // per-process constant -> identical work every call (graph-safe).
  const size_t needA = (statsN + 4 * tenN) * sizeof(float);
  bool planA = (ws_size >= needA);
  float* aout     = planA ? (vws + tenN) : out;
  float* gemм_dst = planA ? out : qws;

  ln_stats_kernel<<<dim3(rows / 4), dim3(256), 0, stream>>>(x, stats);
  qkv_gemm_kernel<<<dim3(12, 64), dim3(256), 0, stream>>>(x, stats, gamma, beta,
                                                          Wqkv, qws, kws, vws);
  attn_kernel<<<dim3(32, 32), dim3(256), 0, stream>>>(qws, kws, vws, R, av, cv, aout);
  out_gemm_kernel<<<dim3(4, 64), dim3(256), 0, stream>>>(aout, Wout, gemм_dst);
  if (!planA) {
    hipMemcpyAsync(out, gemм_dst, (size_t)out_size * sizeof(float),
                   hipMemcpyDeviceToDevice, stream);
  }
}

// Round 3
// 520.571 us; speedup vs baseline: 1.5162x; 1.5162x over previous
//
#include <hip/hip_runtime.h>
#include <math.h>

// Problem constants (fixed by the reference)
#define B_   4
#define N_   2048
#define DIM_ 512
#define T_   16
#define H_   8
#define DH_  64
// num_patches = N/T = 128; 64-wide tiles align inside patches -> decay scalar per tile pair

typedef __attribute__((ext_vector_type(8))) short bf16x8;    // 8 bf16 = 4 VGPRs
typedef __attribute__((ext_vector_type(16))) float f32x16;   // 32x32 MFMA acc

__device__ inline unsigned short bf16_rn(float x) {
  unsigned u = __builtin_bit_cast(unsigned, x);
  u += 0x7FFFu + ((u >> 16) & 1u);
  return (unsigned short)(u >> 16);
}
__device__ inline float bf16f(unsigned short h) {
  return __builtin_bit_cast(float, (unsigned)h << 16);
}
__device__ inline unsigned pack2(unsigned short a, unsigned short b) {
  return (unsigned)a | ((unsigned)b << 16);
}

// ---------------------------------------------------------------------------
// Kernel 1: per-row LayerNorm stats (mu, rstd). One wave per row.
// ---------------------------------------------------------------------------
__global__ __launch_bounds__(256) void ln_stats_kernel(const float* __restrict__ x,
                                                       float* __restrict__ stats) {
  int row  = blockIdx.x * 4 + (threadIdx.x >> 6);
  int lane = threadIdx.x & 63;
  const float4* xr = (const float4*)(x + (size_t)row * DIM_);
  float4 v0 = xr[lane * 2 + 0];
  float4 v1 = xr[lane * 2 + 1];
  float s  = v0.x + v0.y + v0.z + v0.w + v1.x + v1.y + v1.z + v1.w;
  float ss = v0.x*v0.x + v0.y*v0.y + v0.z*v0.z + v0.w*v0.w
           + v1.x*v1.x + v1.y*v1.y + v1.z*v1.z + v1.w*v1.w;
#pragma unroll
  for (int off = 32; off > 0; off >>= 1) {
    s  += __shfl_xor(s, off);
    ss += __shfl_xor(ss, off);
  }
  if (lane == 0) {
    float mu  = s * (1.0f / DIM_);
    float var = ss * (1.0f / DIM_) - mu * mu;
    stats[2 * row + 0] = mu;
    stats[2 * row + 1] = rsqrtf(var + 1e-5f);
  }
}

// ---------------------------------------------------------------------------
// Kernel 2: qkv = LN(x) @ W_qkv, output scattered into q/k/v [B,H,N,DH].
// 128x128 tile, K-step 16, 256 threads, 8x8 per thread (split 4+4 halves).
// ---------------------------------------------------------------------------
__global__ __launch_bounds__(256) void qkv_gemm_kernel(
    const float* __restrict__ x, const float* __restrict__ stats,
    const float* __restrict__ gamma, const float* __restrict__ beta,
    const float* __restrict__ Wqkv,
    float* __restrict__ qo, float* __restrict__ ko, float* __restrict__ vo) {
  __shared__ float At[16][132];
  __shared__ float Bs[16][132];
  int tid = threadIdx.x;
  int tx = tid & 15, ty = tid >> 4;
  int col0 = blockIdx.x * 128;
  int row0 = blockIdx.y * 128;
  float acc[8][8] = {};

  for (int k0 = 0; k0 < DIM_; k0 += 16) {
#pragma unroll
    for (int it = 0; it < 2; ++it) {
      int f = tid + it * 256;
      int r = f >> 2;
      int kc = (f & 3) << 2;
      int grow = row0 + r;
      float4 xv = *(const float4*)&x[(size_t)grow * DIM_ + k0 + kc];
      float mu = stats[2 * grow], rstd = stats[2 * grow + 1];
      At[kc + 0][r] = (xv.x - mu) * rstd * gamma[k0 + kc + 0] + beta[k0 + kc + 0];
      At[kc + 1][r] = (xv.y - mu) * rstd * gamma[k0 + kc + 1] + beta[k0 + kc + 1];
      At[kc + 2][r] = (xv.z - mu) * rstd * gamma[k0 + kc + 2] + beta[k0 + kc + 2];
      At[kc + 3][r] = (xv.w - mu) * rstd * gamma[k0 + kc + 3] + beta[k0 + kc + 3];
    }
#pragma unroll
    for (int it = 0; it < 2; ++it) {
      int f = tid + it * 256;
      int kr = f >> 5;
      int cc = (f & 31) << 2;
      *(float4*)&Bs[kr][cc] = *(const float4*)&Wqkv[(size_t)(k0 + kr) * 1536 + col0 + cc];
    }
    __syncthreads();
#pragma unroll
    for (int kk = 0; kk < 16; ++kk) {
      float4 a0 = *(float4*)&At[kk][ty * 4];
      float4 a1 = *(float4*)&At[kk][64 + ty * 4];
      float4 b0 = *(float4*)&Bs[kk][tx * 4];
      float4 b1 = *(float4*)&Bs[kk][64 + tx * 4];
      float avv[8] = {a0.x, a0.y, a0.z, a0.w, a1.x, a1.y, a1.z, a1.w};
      float bvv[8] = {b0.x, b0.y, b0.z, b0.w, b1.x, b1.y, b1.z, b1.w};
#pragma unroll
      for (int i = 0; i < 8; ++i)
#pragma unroll
        for (int j = 0; j < 8; ++j)
          acc[i][j] = fmaf(avv[i], bvv[j], acc[i][j]);
    }
    __syncthreads();
  }

#pragma unroll
  for (int ih = 0; ih < 2; ++ih) {
#pragma unroll
    for (int i = 0; i < 4; ++i) {
      int grow = row0 + ih * 64 + ty * 4 + i;
      int bb = grow >> 11;
      int n  = grow & 2047;
#pragma unroll
      for (int jh = 0; jh < 2; ++jh) {
        int gcol = col0 + jh * 64 + tx * 4;
        int part = gcol >> 9;
        int rem  = gcol & 511;
        int h = rem >> 6, d = rem & 63;
        float* dst = (part == 0) ? qo : ((part == 1) ? ko : vo);
        float4 o;
        o.x = acc[ih * 4 + i][jh * 4 + 0];
        o.y = acc[ih * 4 + i][jh * 4 + 1];
        o.z = acc[ih * 4 + i][jh * 4 + 2];
        o.w = acc[ih * 4 + i][jh * 4 + 3];
        *(float4*)&dst[(((size_t)bb * H_ + h) * N_ + n) * DH_ + d] = o;
      }
    }
  }
}

// ---------------------------------------------------------------------------
// Kernel 3: MFMA attention (32x32x16 bf16).
// Block = 64 queries x one (b,h), 4 waves. Wave w: q-half = w>>1,
// key-half (QK) / d-half (PV) = w&1.
// S = Qh*Kh + Qh*Kl + Ql*Kh (split-bf16, ~2^-17 exact); P,V plain bf16.
// Softmax has no max-subtraction: logits = relu(s)*dec in [0, ~2].
// C/D layout (m74/m101): col = lane&31, row = (reg&3)+8*(reg>>2)+4*(lane>>5).
// A/B frag: idx = lane&31, k = 8*(lane>>5)+j  -> b128 reads from 72-stride rows.
// ---------------------------------------------------------------------------
__global__ __launch_bounds__(256) void attn_kernel(
    const float* __restrict__ q, const float* __restrict__ k,
    const float* __restrict__ v, const float* __restrict__ R,
    const float* __restrict__ a, const float* __restrict__ c,
    float* __restrict__ aout) {
  __shared__ unsigned short QPh[64 * 72];  // Q-hi; reused as P after frag hoist
  __shared__ unsigned short QPl[64 * 72];  // Q-lo
  __shared__ unsigned short KhS[64 * 72];
  __shared__ unsigned short KlS[64 * 72];
  __shared__ unsigned short VtS[64 * 72];  // V transposed [d][key]
  __shared__ float rsLDS[2][64];

  int tid = threadIdx.x;
  int w = tid >> 6, lane = tid & 63;
  int l31 = lane & 31, g = lane >> 5;
  int qh = w >> 1;
  int kh = w & 1;
  int qt = blockIdx.x;
  int bh = blockIdx.y;
  int b = bh >> 3, h = bh & 7;
  float aab = fabsf(a[h]);
  float cab = fabsf(c[h]);
  const float* qp = q + ((size_t)bh * N_ + qt * 64) * DH_;
  const float* kp = k + (size_t)bh * N_ * DH_;
  const float* vp = v + (size_t)bh * N_ * DH_;

  // ---- stage Q (scale folded) as hi/lo bf16, row stride 72 ----
#pragma unroll
  for (int it = 0; it < 4; ++it) {
    int f = tid + it * 256;
    int row = f >> 4, d4 = (f & 15) << 2;
    float4 xv = *(const float4*)&qp[row * DH_ + d4];
    float x0 = xv.x * 0.125f, x1 = xv.y * 0.125f;
    float x2 = xv.z * 0.125f, x3 = xv.w * 0.125f;
    unsigned short h0 = bf16_rn(x0), h1 = bf16_rn(x1);
    unsigned short h2 = bf16_rn(x2), h3 = bf16_rn(x3);
    unsigned short l0 = bf16_rn(x0 - bf16f(h0)), l1 = bf16_rn(x1 - bf16f(h1));
    unsigned short l2 = bf16_rn(x2 - bf16f(h2)), l3 = bf16_rn(x3 - bf16f(h3));
    int idx = row * 72 + d4;
    *(unsigned*)&QPh[idx]     = pack2(h0, h1);
    *(unsigned*)&QPh[idx + 2] = pack2(h2, h3);
    *(unsigned*)&QPl[idx]     = pack2(l0, l1);
    *(unsigned*)&QPl[idx + 2] = pack2(l2, l3);
  }
  __syncthreads();

  // hoist Q fragments to registers (QPh region then becomes the P buffer)
  int qrow = qh * 32 + l31;
  bf16x8 qfh[4], qfl[4];
#pragma unroll
  for (int d0i = 0; d0i < 4; ++d0i) {
    int off = d0i * 16 + 8 * g;
    qfh[d0i] = *(const bf16x8*)&QPh[qrow * 72 + off];
    qfl[d0i] = *(const bf16x8*)&QPl[qrow * 72 + off];
  }

  f32x16 oacc;
#pragma unroll
  for (int i = 0; i < 16; ++i) oacc[i] = 0.0f;
  float rs_acc[16] = {};
  int ti = qt >> 1;

  for (int kt = 0; kt < 32; ++kt) {
    __syncthreads();  // prev PV done reading P/Vt; prev S done reading K
    // ---- stage K hi/lo ----
#pragma unroll
    for (int it = 0; it < 4; ++it) {
      int f = tid + it * 256;
      int row = f >> 4, d4 = (f & 15) << 2;
      float4 xv = *(const float4*)&kp[(size_t)(kt * 64 + row) * DH_ + d4];
      unsigned short h0 = bf16_rn(xv.x), h1 = bf16_rn(xv.y);
      unsigned short h2 = bf16_rn(xv.z), h3 = bf16_rn(xv.w);
      unsigned short l0 = bf16_rn(xv.x - bf16f(h0)), l1 = bf16_rn(xv.y - bf16f(h1));
      unsigned short l2 = bf16_rn(xv.z - bf16f(h2)), l3 = bf16_rn(xv.w - bf16f(h3));
      int idx = row * 72 + d4;
      *(unsigned*)&KhS[idx]     = pack2(h0, h1);
      *(unsigned*)&KhS[idx + 2] = pack2(h2, h3);
      *(unsigned*)&KlS[idx]     = pack2(l0, l1);
      *(unsigned*)&KlS[idx + 2] = pack2(l2, l3);
    }
    // ---- stage V transposed (key-major lanes -> conflict-free stores) ----
#pragma unroll
    for (int it = 0; it < 4; ++it) {
      int f = tid + it * 256;
      int key = f & 63, d4 = (f >> 6) << 2;
      float4 xv = *(const float4*)&vp[(size_t)(kt * 64 + key) * DH_ + d4];
      VtS[(d4 + 0) * 72 + key] = bf16_rn(xv.x);
      VtS[(d4 + 1) * 72 + key] = bf16_rn(xv.y);
      VtS[(d4 + 2) * 72 + key] = bf16_rn(xv.z);
      VtS[(d4 + 3) * 72 + key] = bf16_rn(xv.w);
    }
    __syncthreads();  // staging visible

    // ---- S = Q K^T (split-bf16, 3 products) ----
    f32x16 sacc;
#pragma unroll
    for (int i = 0; i < 16; ++i) sacc[i] = 0.0f;
    int krow = kh * 32 + l31;
#pragma unroll
    for (int d0i = 0; d0i < 4; ++d0i) {
      int off = d0i * 16 + 8 * g;
      bf16x8 kfh = *(const bf16x8*)&KhS[krow * 72 + off];
      bf16x8 kfl = *(const bf16x8*)&KlS[krow * 72 + off];
      sacc = __builtin_amdgcn_mfma_f32_32x32x16_bf16(qfh[d0i], kfh, sacc, 0, 0, 0);
      sacc = __builtin_amdgcn_mfma_f32_32x32x16_bf16(qfh[d0i], kfl, sacc, 0, 0, 0);
      sacc = __builtin_amdgcn_mfma_f32_32x32x16_bf16(qfl[d0i], kfh, sacc, 0, 0, 0);
    }

    // ---- decay + exp, accumulate row sums, write P (bf16) ----
    float Rv = R[b * (T_ * T_) + ti * T_ + (kt >> 1)];
    float dec = 1.0f / (1.0f + __expf(aab * Rv - cab));
#pragma unroll
    for (int reg = 0; reg < 16; ++reg) {
      float pv = __expf(fmaxf(sacc[reg], 0.0f) * dec);
      rs_acc[reg] += pv;
      int row = (reg & 3) + 8 * (reg >> 2) + 4 * g;
      QPh[(qh * 32 + row) * 72 + kh * 32 + l31] = bf16_rn(pv);
    }
    __syncthreads();  // P visible to both k-half waves

    // ---- O += P V ----
#pragma unroll
    for (int k0i = 0; k0i < 4; ++k0i) {
      int off = k0i * 16 + 8 * g;
      bf16x8 pf = *(const bf16x8*)&QPh[(qh * 32 + l31) * 72 + off];
      bf16x8 vf = *(const bf16x8*)&VtS[(kh * 32 + l31) * 72 + off];
      oacc = __builtin_amdgcn_mfma_f32_32x32x16_bf16(pf, vf, oacc, 0, 0, 0);
    }
  }

  // ---- combine row sums: intra-wave over 32 cols, cross-wave via LDS ----
#pragma unroll
  for (int reg = 0; reg < 16; ++reg) {
    float vsum = rs_acc[reg];
    vsum += __shfl_xor(vsum, 1);
    vsum += __shfl_xor(vsum, 2);
    vsum += __shfl_xor(vsum, 4);
    vsum += __shfl_xor(vsum, 8);
    vsum += __shfl_xor(vsum, 16);
    rs_acc[reg] = vsum;
  }
  if (l31 == 0) {
#pragma unroll
    for (int reg = 0; reg < 16; ++reg) {
      int row = (reg & 3) + 8 * (reg >> 2) + 4 * g;
      rsLDS[kh][qh * 32 + row] = rs_acc[reg];
    }
  }
  __syncthreads();

  // ---- normalize + write attn_out [B][N][H*DH] ----
#pragma unroll
  for (int reg = 0; reg < 16; ++reg) {
    int row = (reg & 3) + 8 * (reg >> 2) + 4 * g;
    int qg = qh * 32 + row;
    float invs = 1.0f / (rsLDS[0][qg] + rsLDS[1][qg]);
    int n = qt * 64 + qg;
    int d = kh * 32 + l31;
    aout[((size_t)b * N_ + n) * (H_ * DH_) + h * DH_ + d] = oacc[reg] * invs;
  }
}

// ---------------------------------------------------------------------------
// Kernel 4: out = attn_out @ W_out. Same 128x128 tiling as kernel 2, no LN.
// ---------------------------------------------------------------------------
__global__ __launch_bounds__(256) void out_gemm_kernel(
    const float* __restrict__ A, const float* __restrict__ Wout,
    float* __restrict__ out) {
  __shared__ float At[16][132];
  __shared__ float Bs[16][132];
  int tid = threadIdx.x;
  int tx = tid & 15, ty = tid >> 4;
  int col0 = blockIdx.x * 128;
  int row0 = blockIdx.y * 128;
  float acc[8][8] = {};

  for (int k0 = 0; k0 < 512; k0 += 16) {
#pragma unroll
    for (int it = 0; it < 2; ++it) {
      int f = tid + it * 256;
      int r = f >> 2;
      int kc = (f & 3) << 2;
      int grow = row0 + r;
      float4 xv = *(const float4*)&A[(size_t)grow * 512 + k0 + kc];
      At[kc + 0][r] = xv.x;
      At[kc + 1][r] = xv.y;
      At[kc + 2][r] = xv.z;
      At[kc + 3][r] = xv.w;
    }
#pragma unroll
    for (int it = 0; it < 2; ++it) {
      int f = tid + it * 256;
      int kr = f >> 5;
      int cc = (f & 31) << 2;
      *(float4*)&Bs[kr][cc] = *(const float4*)&Wout[(size_t)(k0 + kr) * 512 + col0 + cc];
    }
    __syncthreads();
#pragma unroll
    for (int kk = 0; kk < 16; ++kk) {
      float4 a0 = *(float4*)&At[kk][ty * 4];
      float4 a1 = *(float4*)&At[kk][64 + ty * 4];
      float4 b0 = *(float4*)&Bs[kk][tx * 4];
      float4 b1 = *(float4*)&Bs[kk][64 + tx * 4];
      float avv[8] = {a0.x, a0.y, a0.z, a0.w, a1.x, a1.y, a1.z, a1.w};
      float bvv[8] = {b0.x, b0.y, b0.z, b0.w, b1.x, b1.y, b1.z, b1.w};
#pragma unroll
      for (int i = 0; i < 8; ++i)
#pragma unroll
        for (int j = 0; j < 8; ++j)
          acc[i][j] = fmaf(avv[i], bvv[j], acc[i][j]);
    }
    __syncthreads();
  }

#pragma unroll
  for (int ih = 0; ih < 2; ++ih) {
#pragma unroll
    for (int i = 0; i < 4; ++i) {
      int grow = row0 + ih * 64 + ty * 4 + i;
#pragma unroll
      for (int jh = 0; jh < 2; ++jh) {
        int gcol = col0 + jh * 64 + tx * 4;
        float4 o;
        o.x = acc[ih * 4 + i][jh * 4 + 0];
        o.y = acc[ih * 4 + i][jh * 4 + 1];
        o.z = acc[ih * 4 + i][jh * 4 + 2];
        o.w = acc[ih * 4 + i][jh * 4 + 3];
        *(float4*)&out[(size_t)grow * 512 + gcol] = o;
      }
    }
  }
}

// ---------------------------------------------------------------------------
extern "C" void kernel_launch(void* const* d_in, const int* in_sizes, int n_in,
                              void* d_out, int out_size, void* d_ws, size_t ws_size,
                              hipStream_t stream) {
  (void)in_sizes; (void)n_in;
  const float* x     = (const float*)d_in[0];
  const float* R     = (const float*)d_in[1];
  const float* gamma = (const float*)d_in[2];
  const float* beta  = (const float*)d_in[3];
  const float* Wqkv  = (const float*)d_in[4];
  const float* Wout  = (const float*)d_in[5];
  const float* av    = (const float*)d_in[6];
  const float* cv    = (const float*)d_in[7];
  float* out = (float*)d_out;
  float* ws  = (float*)d_ws;

  const size_t rows   = (size_t)B_ * N_;    // 8192
  const size_t statsN = rows * 2;
  const size_t tenN   = rows * DIM_;        // 4194304 floats per tensor

  float* stats = ws;
  float* qws = stats + statsN;
  float* kws = qws + tenN;
  float* vws = kws + tenN;

  const size_t needA = (statsN + 4 * tenN) * sizeof(float);
  bool planA = (ws_size >= needA);
  float* aout     = planA ? (vws + tenN) : out;
  float* gemm_dst = planA ? out : qws;

  ln_stats_kernel<<<dim3(rows / 4), dim3(256), 0, stream>>>(x, stats);
  qkv_gemm_kernel<<<dim3(12, 64), dim3(256), 0, stream>>>(x, stats, gamma, beta,
                                                          Wqkv, qws, kws, vws);
  attn_kernel<<<dim3(32, 32), dim3(256), 0, stream>>>(qws, kws, vws, R, av, cv, aout);
  out_gemm_kernel<<<dim3(4, 64), dim3(256), 0, stream>>>(aout, Wout, gemm_dst);
  if (!planA) {
    hipMemcpyAsync(out, gemm_dst, (size_t)out_size * sizeof(float),
                   hipMemcpyDeviceToDevice, stream);
  }
}

// Round 5
// 499.205 us; speedup vs baseline: 1.5811x; 1.0428x over previous
//
#include <hip/hip_runtime.h>
#include <math.h>

#define B_   4
#define N_   2048
#define DIM_ 512
#define T_   16
#define H_   8
#define DH_  64
// num_patches = 128; 64-token tiles align within patches -> decay scalar per tile pair

typedef unsigned short ushort_t;
typedef __attribute__((ext_vector_type(8))) short bf16x8;    // 8 bf16 = 4 VGPRs
typedef __attribute__((ext_vector_type(16))) float f32x16;   // 32x32 MFMA acc

__device__ inline ushort_t bf16_rn(float x) {
  unsigned u = __builtin_bit_cast(unsigned, x);
  u += 0x7FFFu + ((u >> 16) & 1u);
  return (ushort_t)(u >> 16);
}
__device__ inline float bf16f(ushort_t h) {
  return __builtin_bit_cast(float, (unsigned)h << 16);
}
__device__ inline unsigned pack2(ushort_t a, ushort_t b) {
  return (unsigned)a | ((unsigned)b << 16);
}
__device__ inline void split2(float x, ushort_t &h, ushort_t &l) {
  h = bf16_rn(x);
  l = bf16_rn(x - bf16f(h));
}

// ---------------------------------------------------------------------------
// Kernel A: transpose + hi/lo split of a weight matrix.
// src [K][Nn] fp32 row-major  ->  dh/dl [Nn][K] bf16 hi/lo.
// ---------------------------------------------------------------------------
__global__ __launch_bounds__(256) void transpose_split_kernel(
    const float* __restrict__ src, ushort_t* __restrict__ dh,
    ushort_t* __restrict__ dl, int K, int Nn) {
  __shared__ float Ts[64][68];   // stride 68 floats: 16B-aligned rows, conflict-free
  int tid = threadIdx.x;
  int n0 = blockIdx.x * 64;
  int k0 = blockIdx.y * 64;
#pragma unroll
  for (int it = 0; it < 4; ++it) {
    int idx = tid + it * 256;          // 1024 float4s
    int r = idx >> 4, c4 = (idx & 15) * 4;
    *(float4*)&Ts[r][c4] = *(const float4*)&src[(size_t)(k0 + r) * Nn + n0 + c4];
  }
  __syncthreads();
#pragma unroll
  for (int it = 0; it < 2; ++it) {
    int idx = tid + it * 256;          // 512 output uint4s (per half)
    int n = idx >> 3, kc = (idx & 7) * 8;
    ushort_t hs[8], ls[8];
#pragma unroll
    for (int j = 0; j < 8; ++j) split2(Ts[kc + j][n], hs[j], ls[j]);
    uint4 uh, ul;
    uh.x = pack2(hs[0], hs[1]); uh.y = pack2(hs[2], hs[3]);
    uh.z = pack2(hs[4], hs[5]); uh.w = pack2(hs[6], hs[7]);
    ul.x = pack2(ls[0], ls[1]); ul.y = pack2(ls[2], ls[3]);
    ul.z = pack2(ls[4], ls[5]); ul.w = pack2(ls[6], ls[7]);
    size_t o = (size_t)(n0 + n) * K + k0 + kc;
    *(uint4*)&dh[o] = uh;
    *(uint4*)&dl[o] = ul;
  }
}

// ---------------------------------------------------------------------------
// Kernel B: LayerNorm -> xn hi/lo bf16 [8192][512]. One wave per row.
// ---------------------------------------------------------------------------
__global__ __launch_bounds__(256) void ln_xn_kernel(
    const float* __restrict__ x, const float* __restrict__ gamma,
    const float* __restrict__ beta, ushort_t* __restrict__ xnh,
    ushort_t* __restrict__ xnl) {
  int row  = blockIdx.x * 4 + (threadIdx.x >> 6);
  int lane = threadIdx.x & 63;
  const float4* xr = (const float4*)(x + (size_t)row * DIM_);
  float4 v0 = xr[lane * 2 + 0];
  float4 v1 = xr[lane * 2 + 1];
  float s  = v0.x + v0.y + v0.z + v0.w + v1.x + v1.y + v1.z + v1.w;
  float ss = v0.x*v0.x + v0.y*v0.y + v0.z*v0.z + v0.w*v0.w
           + v1.x*v1.x + v1.y*v1.y + v1.z*v1.z + v1.w*v1.w;
#pragma unroll
  for (int off = 32; off > 0; off >>= 1) {
    s  += __shfl_xor(s, off);
    ss += __shfl_xor(ss, off);
  }
  float mu  = s * (1.0f / DIM_);
  float var = ss * (1.0f / DIM_) - mu * mu;
  float rstd = rsqrtf(var + 1e-5f);
  float4 g0 = *(const float4*)&gamma[lane * 8];
  float4 g1 = *(const float4*)&gamma[lane * 8 + 4];
  float4 b0 = *(const float4*)&beta[lane * 8];
  float4 b1 = *(const float4*)&beta[lane * 8 + 4];
  float xv[8] = {v0.x, v0.y, v0.z, v0.w, v1.x, v1.y, v1.z, v1.w};
  float gv[8] = {g0.x, g0.y, g0.z, g0.w, g1.x, g1.y, g1.z, g1.w};
  float bv[8] = {b0.x, b0.y, b0.z, b0.w, b1.x, b1.y, b1.z, b1.w};
  ushort_t hs[8], ls[8];
#pragma unroll
  for (int j = 0; j < 8; ++j) {
    float xn = (xv[j] - mu) * rstd * gv[j] + bv[j];
    split2(xn, hs[j], ls[j]);
  }
  uint4 uh, ul;
  uh.x = pack2(hs[0], hs[1]); uh.y = pack2(hs[2], hs[3]);
  uh.z = pack2(hs[4], hs[5]); uh.w = pack2(hs[6], hs[7]);
  ul.x = pack2(ls[0], ls[1]); ul.y = pack2(ls[2], ls[3]);
  ul.z = pack2(ls[4], ls[5]); ul.w = pack2(ls[6], ls[7]);
  size_t o = (size_t)row * DIM_ + lane * 8;
  *(uint4*)&xnh[o] = uh;
  *(uint4*)&xnl[o] = ul;
}

// ---------------------------------------------------------------------------
// Kernel C: qkv = xn @ Wqkv^T, split-bf16 3-product MFMA (32x32x16).
// 128x128 tile, K-step 32, 4 waves in 2x2, each wave 64x64 (2x2 accs).
// LDS stride 40 shorts (80 B: 16B-aligned, <=2-way read / <=3-way store).
// Epilogue scatters q(hi/lo, x0.125), k(hi/lo) [bh][tok][d] and v^T [bh][d][tok].
// ---------------------------------------------------------------------------
__global__ __launch_bounds__(256, 3) void qkv_gemm_mfma(
    const ushort_t* __restrict__ xnh, const ushort_t* __restrict__ xnl,
    const ushort_t* __restrict__ wth, const ushort_t* __restrict__ wtl,
    ushort_t* __restrict__ qh, ushort_t* __restrict__ ql,
    ushort_t* __restrict__ kho, ushort_t* __restrict__ klo,
    ushort_t* __restrict__ vt) {
  __shared__ ushort_t Ah[128 * 40], Al[128 * 40], Bh[128 * 40], Bl[128 * 40];
  int tid = threadIdx.x;
  int w = tid >> 6, lane = tid & 63, l31 = lane & 31, g = lane >> 5;
  int wm = w >> 1, wn = w & 1;
  int n0 = blockIdx.x * 128;
  int m0 = blockIdx.y * 128;

  f32x16 acc[2][2];
#pragma unroll
  for (int i = 0; i < 2; ++i)
#pragma unroll
    for (int j = 0; j < 2; ++j)
#pragma unroll
      for (int e = 0; e < 16; ++e) acc[i][j][e] = 0.0f;

  int fm[2], fc[2];
#pragma unroll
  for (int it = 0; it < 2; ++it) {
    int f = tid + it * 256;
    fm[it] = f >> 2;
    fc[it] = (f & 3) * 8;
  }
  uint4 rah[2], ral[2], rbh[2], rbl[2];
#pragma unroll
  for (int it = 0; it < 2; ++it) {
    size_t ao = (size_t)(m0 + fm[it]) * 512 + fc[it];
    size_t bo = (size_t)(n0 + fm[it]) * 512 + fc[it];
    rah[it] = *(const uint4*)&xnh[ao];
    ral[it] = *(const uint4*)&xnl[ao];
    rbh[it] = *(const uint4*)&wth[bo];
    rbl[it] = *(const uint4*)&wtl[bo];
  }

  for (int kt = 0; kt < 16; ++kt) {
    __syncthreads();
#pragma unroll
    for (int it = 0; it < 2; ++it) {
      int o = fm[it] * 40 + fc[it];
      *(uint4*)&Ah[o] = rah[it];
      *(uint4*)&Al[o] = ral[it];
      *(uint4*)&Bh[o] = rbh[it];
      *(uint4*)&Bl[o] = rbl[it];
    }
    __syncthreads();
    int kn = (kt + 1 < 16) ? (kt + 1) * 32 : 0;
#pragma unroll
    for (int it = 0; it < 2; ++it) {
      size_t ao = (size_t)(m0 + fm[it]) * 512 + kn + fc[it];
      size_t bo = (size_t)(n0 + fm[it]) * 512 + kn + fc[it];
      rah[it] = *(const uint4*)&xnh[ao];
      ral[it] = *(const uint4*)&xnl[ao];
      rbh[it] = *(const uint4*)&wth[bo];
      rbl[it] = *(const uint4*)&wtl[bo];
    }
#pragma unroll
    for (int kc = 0; kc < 2; ++kc) {
      int off = kc * 16 + 8 * g;
      bf16x8 afh[2], afl[2], bfh[2], bfl[2];
#pragma unroll
      for (int rb = 0; rb < 2; ++rb) {
        int r = (wm * 64 + rb * 32 + l31) * 40 + off;
        afh[rb] = *(const bf16x8*)&Ah[r];
        afl[rb] = *(const bf16x8*)&Al[r];
      }
#pragma unroll
      for (int cb = 0; cb < 2; ++cb) {
        int r = (wn * 64 + cb * 32 + l31) * 40 + off;
        bfh[cb] = *(const bf16x8*)&Bh[r];
        bfl[cb] = *(const bf16x8*)&Bl[r];
      }
#pragma unroll
      for (int rb = 0; rb < 2; ++rb)
#pragma unroll
        for (int cb = 0; cb < 2; ++cb) {
          acc[rb][cb] = __builtin_amdgcn_mfma_f32_32x32x16_bf16(afh[rb], bfh[cb], acc[rb][cb], 0, 0, 0);
          acc[rb][cb] = __builtin_amdgcn_mfma_f32_32x32x16_bf16(afh[rb], bfl[cb], acc[rb][cb], 0, 0, 0);
          acc[rb][cb] = __builtin_amdgcn_mfma_f32_32x32x16_bf16(afl[rb], bfh[cb], acc[rb][cb], 0, 0, 0);
        }
    }
  }

  // epilogue: part uniform per block (n0: 0-383 q, 512.. k, 1024.. v)
  int part = n0 >> 9;
#pragma unroll
  for (int rb = 0; rb < 2; ++rb) {
    int m_base = m0 + wm * 64 + rb * 32;
#pragma unroll
    for (int cb = 0; cb < 2; ++cb) {
      int n_g = n0 + wn * 64 + cb * 32 + l31;
      int rem = n_g & 511, hh = rem >> 6, d = rem & 63;
      if (part == 2) {
#pragma unroll
        for (int grp = 0; grp < 4; ++grp) {
          int m_g = m_base + grp * 8 + 4 * g;
          int bb = m_g >> 11, tok = m_g & 2047;
          uint2 pk;
          pk.x = pack2(bf16_rn(acc[rb][cb][grp * 4 + 0]), bf16_rn(acc[rb][cb][grp * 4 + 1]));
          pk.y = pack2(bf16_rn(acc[rb][cb][grp * 4 + 2]), bf16_rn(acc[rb][cb][grp * 4 + 3]));
          *(uint2*)&vt[((size_t)(bb * 8 + hh) * 64 + d) * 2048 + tok] = pk;
        }
      } else {
        float sc = (part == 0) ? 0.125f : 1.0f;
        ushort_t* dsth = (part == 0) ? qh : kho;
        ushort_t* dstl = (part == 0) ? ql : klo;
#pragma unroll
        for (int reg = 0; reg < 16; ++reg) {
          int row = (reg & 3) + 8 * (reg >> 2) + 4 * g;
          int m_g = m_base + row;
          int bb = m_g >> 11, tok = m_g & 2047;
          ushort_t hi, lo;
          split2(acc[rb][cb][reg] * sc, hi, lo);
          size_t addr = ((size_t)(bb * 8 + hh) * 2048 + tok) * 64 + d;
          dsth[addr] = hi;
          dstl[addr] = lo;
        }
      }
    }
  }
}

// ---------------------------------------------------------------------------
// Kernel D: MFMA attention, pre-converted bf16 inputs, register prefetch.
// Block = 64 queries x one (b,h), 4 waves (qhalf=w>>1, khalf=w&1).
// S = Qh*Kh + Qh*Kl + Ql*Kh; P,V bf16. No max-subtraction needed.
// LDS stride 72 shorts (R3-verified conflict-free). 4 blocks/CU.
// ---------------------------------------------------------------------------
__global__ __launch_bounds__(256, 4) void attn_mfma(
    const ushort_t* __restrict__ qh, const ushort_t* __restrict__ ql,
    const ushort_t* __restrict__ kho, const ushort_t* __restrict__ klo,
    const ushort_t* __restrict__ vt, const float* __restrict__ R,
    const float* __restrict__ a, const float* __restrict__ c,
    ushort_t* __restrict__ aoh, ushort_t* __restrict__ aol) {
  __shared__ ushort_t KhS[64 * 72], KlS[64 * 72], VtS[64 * 72], PS[64 * 72];
  __shared__ float rsLDS[2][64];

  int tid = threadIdx.x;
  int w = tid >> 6, lane = tid & 63, l31 = lane & 31, g = lane >> 5;
  int qhalf = w >> 1, khalf = w & 1;
  int qt = blockIdx.x;
  int bh = blockIdx.y;
  int b = bh >> 3, h = bh & 7;
  float aab = fabsf(a[h]);
  float cab = fabsf(c[h]);

  // Q fragments straight from global (pre-scaled hi/lo)
  size_t qoff = ((size_t)bh * 2048 + qt * 64 + qhalf * 32 + l31) * 64;
  bf16x8 qfh[4], qfl[4];
#pragma unroll
  for (int d0i = 0; d0i < 4; ++d0i) {
    qfh[d0i] = *(const bf16x8*)&qh[qoff + d0i * 16 + 8 * g];
    qfl[d0i] = *(const bf16x8*)&ql[qoff + d0i * 16 + 8 * g];
  }

  int frow[2], fcc[2];
#pragma unroll
  for (int it = 0; it < 2; ++it) {
    int f = tid + it * 256;
    frow[it] = f >> 3;
    fcc[it] = (f & 7) * 8;
  }
  const ushort_t* kbase = kho + (size_t)bh * 2048 * 64;
  const ushort_t* lbase = klo + (size_t)bh * 2048 * 64;
  const ushort_t* vbase = vt + (size_t)bh * 64 * 2048;

  uint4 rk[2], rl[2], rv[2];
#pragma unroll
  for (int it = 0; it < 2; ++it) {
    rk[it] = *(const uint4*)&kbase[(size_t)frow[it] * 64 + fcc[it]];
    rl[it] = *(const uint4*)&lbase[(size_t)frow[it] * 64 + fcc[it]];
    rv[it] = *(const uint4*)&vbase[(size_t)frow[it] * 2048 + fcc[it]];
  }

  f32x16 oacc;
#pragma unroll
  for (int i = 0; i < 16; ++i) oacc[i] = 0.0f;
  float rs_acc[16] = {};
  int ti = qt >> 1;

  for (int kt = 0; kt < 32; ++kt) {
    __syncthreads();                      // prev PV done -> LDS writable
#pragma unroll
    for (int it = 0; it < 2; ++it) {
      int o = frow[it] * 72 + fcc[it];
      *(uint4*)&KhS[o] = rk[it];
      *(uint4*)&KlS[o] = rl[it];
      *(uint4*)&VtS[o] = rv[it];
    }
    __syncthreads();                      // staging visible
    int ktn = (kt + 1) & 31;              // wrap: constant work per call
#pragma unroll
    for (int it = 0; it < 2; ++it) {
      rk[it] = *(const uint4*)&kbase[(size_t)(ktn * 64 + frow[it]) * 64 + fcc[it]];
      rl[it] = *(const uint4*)&lbase[(size_t)(ktn * 64 + frow[it]) * 64 + fcc[it]];
      rv[it] = *(const uint4*)&vbase[(size_t)frow[it] * 2048 + ktn * 64 + fcc[it]];
    }

    // S = Q K^T (3-product split)
    f32x16 sacc;
#pragma unroll
    for (int i = 0; i < 16; ++i) sacc[i] = 0.0f;
    int krow = (khalf * 32 + l31) * 72;
#pragma unroll
    for (int d0i = 0; d0i < 4; ++d0i) {
      int off = krow + d0i * 16 + 8 * g;
      bf16x8 kfh = *(const bf16x8*)&KhS[off];
      bf16x8 kfl = *(const bf16x8*)&KlS[off];
      sacc = __builtin_amdgcn_mfma_f32_32x32x16_bf16(qfh[d0i], kfh, sacc, 0, 0, 0);
      sacc = __builtin_amdgcn_mfma_f32_32x32x16_bf16(qfh[d0i], kfl, sacc, 0, 0, 0);
      sacc = __builtin_amdgcn_mfma_f32_32x32x16_bf16(qfl[d0i], kfh, sacc, 0, 0, 0);
    }

    float Rv = R[b * (T_ * T_) + ti * T_ + (kt >> 1)];
    float dec = 1.0f / (1.0f + __expf(aab * Rv - cab));
#pragma unroll
    for (int reg = 0; reg < 16; ++reg) {
      float pv = __expf(fmaxf(sacc[reg], 0.0f) * dec);
      rs_acc[reg] += pv;
      int row = (reg & 3) + 8 * (reg >> 2) + 4 * g;
      PS[(qhalf * 32 + row) * 72 + khalf * 32 + l31] = bf16_rn(pv);
    }
    __syncthreads();                      // P visible to both k-half waves

#pragma unroll
    for (int k0i = 0; k0i < 4; ++k0i) {
      bf16x8 pf = *(const bf16x8*)&PS[(qhalf * 32 + l31) * 72 + k0i * 16 + 8 * g];
      bf16x8 vf = *(const bf16x8*)&VtS[(khalf * 32 + l31) * 72 + k0i * 16 + 8 * g];
      oacc = __builtin_amdgcn_mfma_f32_32x32x16_bf16(pf, vf, oacc, 0, 0, 0);
    }
  }

  // row-sum combine
#pragma unroll
  for (int reg = 0; reg < 16; ++reg) {
    float vsum = rs_acc[reg];
    vsum += __shfl_xor(vsum, 1);
    vsum += __shfl_xor(vsum, 2);
    vsum += __shfl_xor(vsum, 4);
    vsum += __shfl_xor(vsum, 8);
    vsum += __shfl_xor(vsum, 16);
    rs_acc[reg] = vsum;
  }
  if (l31 == 0) {
#pragma unroll
    for (int reg = 0; reg < 16; ++reg) {
      int row = (reg & 3) + 8 * (reg >> 2) + 4 * g;
      rsLDS[khalf][qhalf * 32 + row] = rs_acc[reg];
    }
  }
  __syncthreads();

  // normalize + write aout hi/lo [b][tok][h*64+d]
#pragma unroll
  for (int reg = 0; reg < 16; ++reg) {
    int row = (reg & 3) + 8 * (reg >> 2) + 4 * g;
    int qg = qhalf * 32 + row;
    float invs = 1.0f / (rsLDS[0][qg] + rsLDS[1][qg]);
    int tok = qt * 64 + qg;
    int d = khalf * 32 + l31;
    ushort_t hi, lo;
    split2(oacc[reg] * invs, hi, lo);
    size_t addr = ((size_t)b * 2048 + tok) * 512 + h * 64 + d;
    aoh[addr] = hi;
    aol[addr] = lo;
  }
}

// ---------------------------------------------------------------------------
// Kernel E: out = aout @ Wout^T, split-bf16 3-product MFMA. Same body as C.
// ---------------------------------------------------------------------------
__global__ __launch_bounds__(256, 3) void out_gemm_mfma(
    const ushort_t* __restrict__ ah, const ushort_t* __restrict__ al,
    const ushort_t* __restrict__ wth, const ushort_t* __restrict__ wtl,
    float* __restrict__ out) {
  __shared__ ushort_t Ah[128 * 40], Al[128 * 40], Bh[128 * 40], Bl[128 * 40];
  int tid = threadIdx.x;
  int w = tid >> 6, lane = tid & 63, l31 = lane & 31, g = lane >> 5;
  int wm = w >> 1, wn = w & 1;
  int n0 = blockIdx.x * 128;
  int m0 = blockIdx.y * 128;

  f32x16 acc[2][2];
#pragma unroll
  for (int i = 0; i < 2; ++i)
#pragma unroll
    for (int j = 0; j < 2; ++j)
#pragma unroll
      for (int e = 0; e < 16; ++e) acc[i][j][e] = 0.0f;

  int fm[2], fc[2];
#pragma unroll
  for (int it = 0; it < 2; ++it) {
    int f = tid + it * 256;
    fm[it] = f >> 2;
    fc[it] = (f & 3) * 8;
  }
  uint4 rah[2], ral[2], rbh[2], rbl[2];
#pragma unroll
  for (int it = 0; it < 2; ++it) {
    size_t ao = (size_t)(m0 + fm[it]) * 512 + fc[it];
    size_t bo = (size_t)(n0 + fm[it]) * 512 + fc[it];
    rah[it] = *(const uint4*)&ah[ao];
    ral[it] = *(const uint4*)&al[ao];
    rbh[it] = *(const uint4*)&wth[bo];
    rbl[it] = *(const uint4*)&wtl[bo];
  }

  for (int kt = 0; kt < 16; ++kt) {
    __syncthreads();
#pragma unroll
    for (int it = 0; it < 2; ++it) {
      int o = fm[it] * 40 + fc[it];
      *(uint4*)&Ah[o] = rah[it];
      *(uint4*)&Al[o] = ral[it];
      *(uint4*)&Bh[o] = rbh[it];
      *(uint4*)&Bl[o] = rbl[it];
    }
    __syncthreads();
    int kn = (kt + 1 < 16) ? (kt + 1) * 32 : 0;
#pragma unroll
    for (int it = 0; it < 2; ++it) {
      size_t ao = (size_t)(m0 + fm[it]) * 512 + kn + fc[it];
      size_t bo = (size_t)(n0 + fm[it]) * 512 + kn + fc[it];
      rah[it] = *(const uint4*)&ah[ao];
      ral[it] = *(const uint4*)&al[ao];
      rbh[it] = *(const uint4*)&wth[bo];
      rbl[it] = *(const uint4*)&wtl[bo];
    }
#pragma unroll
    for (int kc = 0; kc < 2; ++kc) {
      int off = kc * 16 + 8 * g;
      bf16x8 afh[2], afl[2], bfh[2], bfl[2];
#pragma unroll
      for (int rb = 0; rb < 2; ++rb) {
        int r = (wm * 64 + rb * 32 + l31) * 40 + off;
        afh[rb] = *(const bf16x8*)&Ah[r];
        afl[rb] = *(const bf16x8*)&Al[r];
      }
#pragma unroll
      for (int cb = 0; cb < 2; ++cb) {
        int r = (wn * 64 + cb * 32 + l31) * 40 + off;
        bfh[cb] = *(const bf16x8*)&Bh[r];
        bfl[cb] = *(const bf16x8*)&Bl[r];
      }
#pragma unroll
      for (int rb = 0; rb < 2; ++rb)
#pragma unroll
        for (int cb = 0; cb < 2; ++cb) {
          acc[rb][cb] = __builtin_amdgcn_mfma_f32_32x32x16_bf16(afh[rb], bfh[cb], acc[rb][cb], 0, 0, 0);
          acc[rb][cb] = __builtin_amdgcn_mfma_f32_32x32x16_bf16(afh[rb], bfl[cb], acc[rb][cb], 0, 0, 0);
          acc[rb][cb] = __builtin_amdgcn_mfma_f32_32x32x16_bf16(afl[rb], bfh[cb], acc[rb][cb], 0, 0, 0);
        }
    }
  }

#pragma unroll
  for (int rb = 0; rb < 2; ++rb) {
    int m_base = m0 + wm * 64 + rb * 32;
#pragma unroll
    for (int cb = 0; cb < 2; ++cb) {
      int n_g = n0 + wn * 64 + cb * 32 + l31;
#pragma unroll
      for (int reg = 0; reg < 16; ++reg) {
        int row = (reg & 3) + 8 * (reg >> 2) + 4 * g;
        out[(size_t)(m_base + row) * 512 + n_g] = acc[rb][cb][reg];
      }
    }
  }
}

// ---------------------------------------------------------------------------
extern "C" void kernel_launch(void* const* d_in, const int* in_sizes, int n_in,
                              void* d_out, int out_size, void* d_ws, size_t ws_size,
                              hipStream_t stream) {
  (void)in_sizes; (void)n_in;
  const float* x     = (const float*)d_in[0];
  const float* R     = (const float*)d_in[1];
  const float* gamma = (const float*)d_in[2];
  const float* beta  = (const float*)d_in[3];
  const float* Wqkv  = (const float*)d_in[4];
  const float* Wout  = (const float*)d_in[5];
  const float* av    = (const float*)d_in[6];
  const float* cv    = (const float*)d_in[7];
  float* out = (float*)d_out;

  const size_t EL  = (size_t)B_ * N_ * DIM_;     // 4,194,304 elements
  const size_t SZT = EL * sizeof(ushort_t);      // 8 MiB per bf16 tensor

  char* p = (char*)d_ws;
  ushort_t* wqh = (ushort_t*)p;                  p += (size_t)1536 * 512 * 2;
  ushort_t* wql = (ushort_t*)p;                  p += (size_t)1536 * 512 * 2;
  ushort_t* woh = (ushort_t*)p;                  p += (size_t)512 * 512 * 2;
  ushort_t* wol = (ushort_t*)p;                  p += (size_t)512 * 512 * 2;
  ushort_t* qhb = (ushort_t*)p;                  p += SZT;
  ushort_t* qlb = (ushort_t*)p;                  p += SZT;
  ushort_t* khb = (ushort_t*)p;                  p += SZT;
  ushort_t* klb = (ushort_t*)p;                  p += SZT;
  ushort_t* vtb = (ushort_t*)p;                  p += SZT;
  size_t base_need = (size_t)(p - (char*)d_ws);
  size_t needA = base_need + 2 * SZT;

  bool planA = (ws_size >= needA);
  // xn hi/lo doubles as aout hi/lo (xn dead after qkv_gemm).
  ushort_t* xnh = planA ? (ushort_t*)p : (ushort_t*)d_out;
  ushort_t* xnl = xnh + EL;
  float* gemm_dst = planA ? out : (float*)qhb;   // qh+ql region = 16.8 MB, dead by then

  transpose_split_kernel<<<dim3(24, 8), dim3(256), 0, stream>>>(Wqkv, wqh, wql, 512, 1536);
  transpose_split_kernel<<<dim3(8, 8), dim3(256), 0, stream>>>(Wout, woh, wol, 512, 512);
  ln_xn_kernel<<<dim3(2048), dim3(256), 0, stream>>>(x, gamma, beta, xnh, xnl);
  qkv_gemm_mfma<<<dim3(12, 64), dim3(256), 0, stream>>>(xnh, xnl, wqh, wql,
                                                        qhb, qlb, khb, klb, vtb);
  attn_mfma<<<dim3(32, 32), dim3(256), 0, stream>>>(qhb, qlb, khb, klb, vtb,
                                                    R, av, cv, xnh, xnl);
  out_gemm_mfma<<<dim3(4, 64), dim3(256), 0, stream>>>(xnh, xnl, woh, wol, gemm_dst);
  if (!planA) {
    hipMemcpyAsync(out, gemm_dst, (size_t)out_size * sizeof(float),
                   hipMemcpyDeviceToDevice, stream);
  }
}

// Round 6
// 494.840 us; speedup vs baseline: 1.5950x; 1.0088x over previous
//
#include <hip/hip_runtime.h>
#include <math.h>

#define B_   4
#define N_   2048
#define DIM_ 512
#define T_   16
#define H_   8
#define DH_  64
// num_patches = 128; 64-token tiles align within patches -> decay scalar per tile pair

typedef unsigned short ushort_t;
typedef __attribute__((ext_vector_type(8))) short bf16x8;    // 8 bf16 = 4 VGPRs
typedef __attribute__((ext_vector_type(16))) float f32x16;   // 32x32 MFMA acc

__device__ inline ushort_t bf16_rn(float x) {
  unsigned u = __builtin_bit_cast(unsigned, x);
  u += 0x7FFFu + ((u >> 16) & 1u);
  return (ushort_t)(u >> 16);
}
__device__ inline float bf16f(ushort_t h) {
  return __builtin_bit_cast(float, (unsigned)h << 16);
}
__device__ inline unsigned pack2(ushort_t a, ushort_t b) {
  return (unsigned)a | ((unsigned)b << 16);
}
__device__ inline void split2(float x, ushort_t &h, ushort_t &l) {
  h = bf16_rn(x);
  l = bf16_rn(x - bf16f(h));
}

// ---------------------------------------------------------------------------
// Kernel A: transpose + hi/lo split of a weight matrix.
// src [K][Nn] fp32 row-major  ->  dh/dl [Nn][K] bf16 hi/lo.
// ---------------------------------------------------------------------------
__global__ __launch_bounds__(256) void transpose_split_kernel(
    const float* __restrict__ src, ushort_t* __restrict__ dh,
    ushort_t* __restrict__ dl, int K, int Nn) {
  __shared__ float Ts[64][68];   // stride 68 floats: 16B-aligned rows, conflict-free
  int tid = threadIdx.x;
  int n0 = blockIdx.x * 64;
  int k0 = blockIdx.y * 64;
#pragma unroll
  for (int it = 0; it < 4; ++it) {
    int idx = tid + it * 256;          // 1024 float4s
    int r = idx >> 4, c4 = (idx & 15) * 4;
    *(float4*)&Ts[r][c4] = *(const float4*)&src[(size_t)(k0 + r) * Nn + n0 + c4];
  }
  __syncthreads();
#pragma unroll
  for (int it = 0; it < 2; ++it) {
    int idx = tid + it * 256;          // 512 output uint4s (per half)
    int n = idx >> 3, kc = (idx & 7) * 8;
    ushort_t hs[8], ls[8];
#pragma unroll
    for (int j = 0; j < 8; ++j) split2(Ts[kc + j][n], hs[j], ls[j]);
    uint4 uh, ul;
    uh.x = pack2(hs[0], hs[1]); uh.y = pack2(hs[2], hs[3]);
    uh.z = pack2(hs[4], hs[5]); uh.w = pack2(hs[6], hs[7]);
    ul.x = pack2(ls[0], ls[1]); ul.y = pack2(ls[2], ls[3]);
    ul.z = pack2(ls[4], ls[5]); ul.w = pack2(ls[6], ls[7]);
    size_t o = (size_t)(n0 + n) * K + k0 + kc;
    *(uint4*)&dh[o] = uh;
    *(uint4*)&dl[o] = ul;
  }
}

// ---------------------------------------------------------------------------
// Kernel B: LayerNorm -> xn hi/lo bf16 [8192][512]. One wave per row.
// ---------------------------------------------------------------------------
__global__ __launch_bounds__(256) void ln_xn_kernel(
    const float* __restrict__ x, const float* __restrict__ gamma,
    const float* __restrict__ beta, ushort_t* __restrict__ xnh,
    ushort_t* __restrict__ xnl) {
  int row  = blockIdx.x * 4 + (threadIdx.x >> 6);
  int lane = threadIdx.x & 63;
  const float4* xr = (const float4*)(x + (size_t)row * DIM_);
  float4 v0 = xr[lane * 2 + 0];
  float4 v1 = xr[lane * 2 + 1];
  float s  = v0.x + v0.y + v0.z + v0.w + v1.x + v1.y + v1.z + v1.w;
  float ss = v0.x*v0.x + v0.y*v0.y + v0.z*v0.z + v0.w*v0.w
           + v1.x*v1.x + v1.y*v1.y + v1.z*v1.z + v1.w*v1.w;
#pragma unroll
  for (int off = 32; off > 0; off >>= 1) {
    s  += __shfl_xor(s, off);
    ss += __shfl_xor(ss, off);
  }
  float mu  = s * (1.0f / DIM_);
  float var = ss * (1.0f / DIM_) - mu * mu;
  float rstd = rsqrtf(var + 1e-5f);
  float4 g0 = *(const float4*)&gamma[lane * 8];
  float4 g1 = *(const float4*)&gamma[lane * 8 + 4];
  float4 b0 = *(const float4*)&beta[lane * 8];
  float4 b1 = *(const float4*)&beta[lane * 8 + 4];
  float xv[8] = {v0.x, v0.y, v0.z, v0.w, v1.x, v1.y, v1.z, v1.w};
  float gv[8] = {g0.x, g0.y, g0.z, g0.w, g1.x, g1.y, g1.z, g1.w};
  float bv[8] = {b0.x, b0.y, b0.z, b0.w, b1.x, b1.y, b1.z, b1.w};
  ushort_t hs[8], ls[8];
#pragma unroll
  for (int j = 0; j < 8; ++j) {
    float xn = (xv[j] - mu) * rstd * gv[j] + bv[j];
    split2(xn, hs[j], ls[j]);
  }
  uint4 uh, ul;
  uh.x = pack2(hs[0], hs[1]); uh.y = pack2(hs[2], hs[3]);
  uh.z = pack2(hs[4], hs[5]); uh.w = pack2(hs[6], hs[7]);
  ul.x = pack2(ls[0], ls[1]); ul.y = pack2(ls[2], ls[3]);
  ul.z = pack2(ls[4], ls[5]); ul.w = pack2(ls[6], ls[7]);
  size_t o = (size_t)row * DIM_ + lane * 8;
  *(uint4*)&xnh[o] = uh;
  *(uint4*)&xnl[o] = ul;
}

// ---------------------------------------------------------------------------
// Kernel C: qkv = xn @ Wqkv^T, split-bf16 3-product MFMA (32x32x16).
// 128x128 tile, K-step 32, 4 waves in 2x2, each wave 64x64 (2x2 accs).
// (256,2): 256-VGPR budget -- acc(64)+staging(64)+frags fit with NO spills.
// Epilogue scatters q(hi/lo, x0.125), k(hi/lo) [bh][tok][d] and v^T [bh][d][tok].
// ---------------------------------------------------------------------------
__global__ __launch_bounds__(256, 2) void qkv_gemm_mfma(
    const ushort_t* __restrict__ xnh, const ushort_t* __restrict__ xnl,
    const ushort_t* __restrict__ wth, const ushort_t* __restrict__ wtl,
    ushort_t* __restrict__ qh, ushort_t* __restrict__ ql,
    ushort_t* __restrict__ kho, ushort_t* __restrict__ klo,
    ushort_t* __restrict__ vt) {
  __shared__ ushort_t Ah[128 * 40], Al[128 * 40], Bh[128 * 40], Bl[128 * 40];
  int tid = threadIdx.x;
  int w = tid >> 6, lane = tid & 63, l31 = lane & 31, g = lane >> 5;
  int wm = w >> 1, wn = w & 1;
  int n0 = blockIdx.x * 128;
  int m0 = blockIdx.y * 128;

  f32x16 acc[2][2];
#pragma unroll
  for (int i = 0; i < 2; ++i)
#pragma unroll
    for (int j = 0; j < 2; ++j)
#pragma unroll
      for (int e = 0; e < 16; ++e) acc[i][j][e] = 0.0f;

  int fm[2], fc[2];
#pragma unroll
  for (int it = 0; it < 2; ++it) {
    int f = tid + it * 256;
    fm[it] = f >> 2;
    fc[it] = (f & 3) * 8;
  }
  uint4 rah[2], ral[2], rbh[2], rbl[2];
#pragma unroll
  for (int it = 0; it < 2; ++it) {
    size_t ao = (size_t)(m0 + fm[it]) * 512 + fc[it];
    size_t bo = (size_t)(n0 + fm[it]) * 512 + fc[it];
    rah[it] = *(const uint4*)&xnh[ao];
    ral[it] = *(const uint4*)&xnl[ao];
    rbh[it] = *(const uint4*)&wth[bo];
    rbl[it] = *(const uint4*)&wtl[bo];
  }

  for (int kt = 0; kt < 16; ++kt) {
    __syncthreads();
#pragma unroll
    for (int it = 0; it < 2; ++it) {
      int o = fm[it] * 40 + fc[it];
      *(uint4*)&Ah[o] = rah[it];
      *(uint4*)&Al[o] = ral[it];
      *(uint4*)&Bh[o] = rbh[it];
      *(uint4*)&Bl[o] = rbl[it];
    }
    __syncthreads();
    int kn = (kt + 1 < 16) ? (kt + 1) * 32 : 0;
#pragma unroll
    for (int it = 0; it < 2; ++it) {
      size_t ao = (size_t)(m0 + fm[it]) * 512 + kn + fc[it];
      size_t bo = (size_t)(n0 + fm[it]) * 512 + kn + fc[it];
      rah[it] = *(const uint4*)&xnh[ao];
      ral[it] = *(const uint4*)&xnl[ao];
      rbh[it] = *(const uint4*)&wth[bo];
      rbl[it] = *(const uint4*)&wtl[bo];
    }
#pragma unroll
    for (int kc = 0; kc < 2; ++kc) {
      int off = kc * 16 + 8 * g;
      bf16x8 afh[2], afl[2], bfh[2], bfl[2];
#pragma unroll
      for (int rb = 0; rb < 2; ++rb) {
        int r = (wm * 64 + rb * 32 + l31) * 40 + off;
        afh[rb] = *(const bf16x8*)&Ah[r];
        afl[rb] = *(const bf16x8*)&Al[r];
      }
#pragma unroll
      for (int cb = 0; cb < 2; ++cb) {
        int r = (wn * 64 + cb * 32 + l31) * 40 + off;
        bfh[cb] = *(const bf16x8*)&Bh[r];
        bfl[cb] = *(const bf16x8*)&Bl[r];
      }
#pragma unroll
      for (int rb = 0; rb < 2; ++rb)
#pragma unroll
        for (int cb = 0; cb < 2; ++cb) {
          acc[rb][cb] = __builtin_amdgcn_mfma_f32_32x32x16_bf16(afh[rb], bfh[cb], acc[rb][cb], 0, 0, 0);
          acc[rb][cb] = __builtin_amdgcn_mfma_f32_32x32x16_bf16(afh[rb], bfl[cb], acc[rb][cb], 0, 0, 0);
          acc[rb][cb] = __builtin_amdgcn_mfma_f32_32x32x16_bf16(afl[rb], bfh[cb], acc[rb][cb], 0, 0, 0);
        }
    }
  }

  // epilogue: part uniform per block (n0: 0-383 q, 512.. k, 1024.. v)
  int part = n0 >> 9;
#pragma unroll
  for (int rb = 0; rb < 2; ++rb) {
    int m_base = m0 + wm * 64 + rb * 32;
#pragma unroll
    for (int cb = 0; cb < 2; ++cb) {
      int n_g = n0 + wn * 64 + cb * 32 + l31;
      int rem = n_g & 511, hh = rem >> 6, d = rem & 63;
      if (part == 2) {
#pragma unroll
        for (int grp = 0; grp < 4; ++grp) {
          int m_g = m_base + grp * 8 + 4 * g;
          int bb = m_g >> 11, tok = m_g & 2047;
          uint2 pk;
          pk.x = pack2(bf16_rn(acc[rb][cb][grp * 4 + 0]), bf16_rn(acc[rb][cb][grp * 4 + 1]));
          pk.y = pack2(bf16_rn(acc[rb][cb][grp * 4 + 2]), bf16_rn(acc[rb][cb][grp * 4 + 3]));
          *(uint2*)&vt[((size_t)(bb * 8 + hh) * 64 + d) * 2048 + tok] = pk;
        }
      } else {
        float sc = (part == 0) ? 0.125f : 1.0f;
        ushort_t* dsth = (part == 0) ? qh : kho;
        ushort_t* dstl = (part == 0) ? ql : klo;
#pragma unroll
        for (int reg = 0; reg < 16; ++reg) {
          int row = (reg & 3) + 8 * (reg >> 2) + 4 * g;
          int m_g = m_base + row;
          int bb = m_g >> 11, tok = m_g & 2047;
          ushort_t hi, lo;
          split2(acc[rb][cb][reg] * sc, hi, lo);
          size_t addr = ((size_t)(bb * 8 + hh) * 2048 + tok) * 64 + d;
          dsth[addr] = hi;
          dstl[addr] = lo;
        }
      }
    }
  }
}

// ---------------------------------------------------------------------------
// Kernel D: MFMA attention, pre-converted bf16 inputs, register prefetch.
// grid: x = bh (XCD affinity: all q-tiles of one bh land on XCD bh%8),
//       y = qt. Block = 64 queries x one (b,h), 4 waves.
// (256,3): 170-VGPR budget -- fits ~150 live regs, no scratch spills
// (R5's (256,4)=128 cap spilled: WRITE_SIZE 733 MB vs 16 MB legit).
// S = Qh*Kh + Qh*Kl + Ql*Kh; P,V bf16. No max-subtraction needed.
// LDS stride 72 shorts (conflict-free, R3/R5: SQ_LDS_BANK_CONFLICT=0).
// ---------------------------------------------------------------------------
__global__ __launch_bounds__(256, 3) void attn_mfma(
    const ushort_t* __restrict__ qh, const ushort_t* __restrict__ ql,
    const ushort_t* __restrict__ kho, const ushort_t* __restrict__ klo,
    const ushort_t* __restrict__ vt, const float* __restrict__ R,
    const float* __restrict__ a, const float* __restrict__ c,
    ushort_t* __restrict__ aoh, ushort_t* __restrict__ aol) {
  __shared__ ushort_t KhS[64 * 72], KlS[64 * 72], VtS[64 * 72], PS[64 * 72];
  __shared__ float rsLDS[2][64];

  int tid = threadIdx.x;
  int w = tid >> 6, lane = tid & 63, l31 = lane & 31, g = lane >> 5;
  int qhalf = w >> 1, khalf = w & 1;
  int bh = blockIdx.x;               // XCD-affinity swizzle
  int qt = blockIdx.y;
  int b = bh >> 3, h = bh & 7;
  float aab = fabsf(a[h]);
  float cab = fabsf(c[h]);

  // Q fragments straight from global (pre-scaled hi/lo)
  size_t qoff = ((size_t)bh * 2048 + qt * 64 + qhalf * 32 + l31) * 64;
  bf16x8 qfh[4], qfl[4];
#pragma unroll
  for (int d0i = 0; d0i < 4; ++d0i) {
    qfh[d0i] = *(const bf16x8*)&qh[qoff + d0i * 16 + 8 * g];
    qfl[d0i] = *(const bf16x8*)&ql[qoff + d0i * 16 + 8 * g];
  }

  int frow[2], fcc[2];
#pragma unroll
  for (int it = 0; it < 2; ++it) {
    int f = tid + it * 256;
    frow[it] = f >> 3;
    fcc[it] = (f & 7) * 8;
  }
  const ushort_t* kbase = kho + (size_t)bh * 2048 * 64;
  const ushort_t* lbase = klo + (size_t)bh * 2048 * 64;
  const ushort_t* vbase = vt + (size_t)bh * 64 * 2048;

  uint4 rk[2], rl[2], rv[2];
#pragma unroll
  for (int it = 0; it < 2; ++it) {
    rk[it] = *(const uint4*)&kbase[(size_t)frow[it] * 64 + fcc[it]];
    rl[it] = *(const uint4*)&lbase[(size_t)frow[it] * 64 + fcc[it]];
    rv[it] = *(const uint4*)&vbase[(size_t)frow[it] * 2048 + fcc[it]];
  }

  f32x16 oacc;
#pragma unroll
  for (int i = 0; i < 16; ++i) oacc[i] = 0.0f;
  float rs_acc[16] = {};
  int ti = qt >> 1;

  for (int kt = 0; kt < 32; ++kt) {
    __syncthreads();                      // prev PV done -> LDS writable
#pragma unroll
    for (int it = 0; it < 2; ++it) {
      int o = frow[it] * 72 + fcc[it];
      *(uint4*)&KhS[o] = rk[it];
      *(uint4*)&KlS[o] = rl[it];
      *(uint4*)&VtS[o] = rv[it];
    }
    __syncthreads();                      // staging visible
    int ktn = (kt + 1) & 31;              // wrap: constant work per call
#pragma unroll
    for (int it = 0; it < 2; ++it) {
      rk[it] = *(const uint4*)&kbase[(size_t)(ktn * 64 + frow[it]) * 64 + fcc[it]];
      rl[it] = *(const uint4*)&lbase[(size_t)(ktn * 64 + frow[it]) * 64 + fcc[it]];
      rv[it] = *(const uint4*)&vbase[(size_t)frow[it] * 2048 + ktn * 64 + fcc[it]];
    }

    // S = Q K^T (3-product split)
    f32x16 sacc;
#pragma unroll
    for (int i = 0; i < 16; ++i) sacc[i] = 0.0f;
    int krow = (khalf * 32 + l31) * 72;
#pragma unroll
    for (int d0i = 0; d0i < 4; ++d0i) {
      int off = krow + d0i * 16 + 8 * g;
      bf16x8 kfh = *(const bf16x8*)&KhS[off];
      bf16x8 kfl = *(const bf16x8*)&KlS[off];
      sacc = __builtin_amdgcn_mfma_f32_32x32x16_bf16(qfh[d0i], kfh, sacc, 0, 0, 0);
      sacc = __builtin_amdgcn_mfma_f32_32x32x16_bf16(qfh[d0i], kfl, sacc, 0, 0, 0);
      sacc = __builtin_amdgcn_mfma_f32_32x32x16_bf16(qfl[d0i], kfh, sacc, 0, 0, 0);
    }

    float Rv = R[b * (T_ * T_) + ti * T_ + (kt >> 1)];
    float dec = 1.0f / (1.0f + __expf(aab * Rv - cab));
#pragma unroll
    for (int reg = 0; reg < 16; ++reg) {
      float pv = __expf(fmaxf(sacc[reg], 0.0f) * dec);
      rs_acc[reg] += pv;
      int row = (reg & 3) + 8 * (reg >> 2) + 4 * g;
      PS[(qhalf * 32 + row) * 72 + khalf * 32 + l31] = bf16_rn(pv);
    }
    __syncthreads();                      // P visible to both k-half waves

#pragma unroll
    for (int k0i = 0; k0i < 4; ++k0i) {
      bf16x8 pf = *(const bf16x8*)&PS[(qhalf * 32 + l31) * 72 + k0i * 16 + 8 * g];
      bf16x8 vf = *(const bf16x8*)&VtS[(khalf * 32 + l31) * 72 + k0i * 16 + 8 * g];
      oacc = __builtin_amdgcn_mfma_f32_32x32x16_bf16(pf, vf, oacc, 0, 0, 0);
    }
  }

  // row-sum combine
#pragma unroll
  for (int reg = 0; reg < 16; ++reg) {
    float vsum = rs_acc[reg];
    vsum += __shfl_xor(vsum, 1);
    vsum += __shfl_xor(vsum, 2);
    vsum += __shfl_xor(vsum, 4);
    vsum += __shfl_xor(vsum, 8);
    vsum += __shfl_xor(vsum, 16);
    rs_acc[reg] = vsum;
  }
  if (l31 == 0) {
#pragma unroll
    for (int reg = 0; reg < 16; ++reg) {
      int row = (reg & 3) + 8 * (reg >> 2) + 4 * g;
      rsLDS[khalf][qhalf * 32 + row] = rs_acc[reg];
    }
  }
  __syncthreads();

  // normalize + write aout hi/lo [b][tok][h*64+d]
#pragma unroll
  for (int reg = 0; reg < 16; ++reg) {
    int row = (reg & 3) + 8 * (reg >> 2) + 4 * g;
    int qg = qhalf * 32 + row;
    float invs = 1.0f / (rsLDS[0][qg] + rsLDS[1][qg]);
    int tok = qt * 64 + qg;
    int d = khalf * 32 + l31;
    ushort_t hi, lo;
    split2(oacc[reg] * invs, hi, lo);
    size_t addr = ((size_t)b * 2048 + tok) * 512 + h * 64 + d;
    aoh[addr] = hi;
    aol[addr] = lo;
  }
}

// ---------------------------------------------------------------------------
// Kernel E: out = aout @ Wout^T, split-bf16 3-product MFMA. Same body as C.
// ---------------------------------------------------------------------------
__global__ __launch_bounds__(256, 2) void out_gemm_mfma(
    const ushort_t* __restrict__ ah, const ushort_t* __restrict__ al,
    const ushort_t* __restrict__ wth, const ushort_t* __restrict__ wtl,
    float* __restrict__ out) {
  __shared__ ushort_t Ah[128 * 40], Al[128 * 40], Bh[128 * 40], Bl[128 * 40];
  int tid = threadIdx.x;
  int w = tid >> 6, lane = tid & 63, l31 = lane & 31, g = lane >> 5;
  int wm = w >> 1, wn = w & 1;
  int n0 = blockIdx.x * 128;
  int m0 = blockIdx.y * 128;

  f32x16 acc[2][2];
#pragma unroll
  for (int i = 0; i < 2; ++i)
#pragma unroll
    for (int j = 0; j < 2; ++j)
#pragma unroll
      for (int e = 0; e < 16; ++e) acc[i][j][e] = 0.0f;

  int fm[2], fc[2];
#pragma unroll
  for (int it = 0; it < 2; ++it) {
    int f = tid + it * 256;
    fm[it] = f >> 2;
    fc[it] = (f & 3) * 8;
  }
  uint4 rah[2], ral[2], rbh[2], rbl[2];
#pragma unroll
  for (int it = 0; it < 2; ++it) {
    size_t ao = (size_t)(m0 + fm[it]) * 512 + fc[it];
    size_t bo = (size_t)(n0 + fm[it]) * 512 + fc[it];
    rah[it] = *(const uint4*)&ah[ao];
    ral[it] = *(const uint4*)&al[ao];
    rbh[it] = *(const uint4*)&wth[bo];
    rbl[it] = *(const uint4*)&wtl[bo];
  }

  for (int kt = 0; kt < 16; ++kt) {
    __syncthreads();
#pragma unroll
    for (int it = 0; it < 2; ++it) {
      int o = fm[it] * 40 + fc[it];
      *(uint4*)&Ah[o] = rah[it];
      *(uint4*)&Al[o] = ral[it];
      *(uint4*)&Bh[o] = rbh[it];
      *(uint4*)&Bl[o] = rbl[it];
    }
    __syncthreads();
    int kn = (kt + 1 < 16) ? (kt + 1) * 32 : 0;
#pragma unroll
    for (int it = 0; it < 2; ++it) {
      size_t ao = (size_t)(m0 + fm[it]) * 512 + kn + fc[it];
      size_t bo = (size_t)(n0 + fm[it]) * 512 + kn + fc[it];
      rah[it] = *(const uint4*)&ah[ao];
      ral[it] = *(const uint4*)&al[ao];
      rbh[it] = *(const uint4*)&wth[bo];
      rbl[it] = *(const uint4*)&wtl[bo];
    }
#pragma unroll
    for (int kc = 0; kc < 2; ++kc) {
      int off = kc * 16 + 8 * g;
      bf16x8 afh[2], afl[2], bfh[2], bfl[2];
#pragma unroll
      for (int rb = 0; rb < 2; ++rb) {
        int r = (wm * 64 + rb * 32 + l31) * 40 + off;
        afh[rb] = *(const bf16x8*)&Ah[r];
        afl[rb] = *(const bf16x8*)&Al[r];
      }
#pragma unroll
      for (int cb = 0; cb < 2; ++cb) {
        int r = (wn * 64 + cb * 32 + l31) * 40 + off;
        bfh[cb] = *(const bf16x8*)&Bh[r];
        bfl[cb] = *(const bf16x8*)&Bl[r];
      }
#pragma unroll
      for (int rb = 0; rb < 2; ++rb)
#pragma unroll
        for (int cb = 0; cb < 2; ++cb) {
          acc[rb][cb] = __builtin_amdgcn_mfma_f32_32x32x16_bf16(afh[rb], bfh[cb], acc[rb][cb], 0, 0, 0);
          acc[rb][cb] = __builtin_amdgcn_mfma_f32_32x32x16_bf16(afh[rb], bfl[cb], acc[rb][cb], 0, 0, 0);
          acc[rb][cb] = __builtin_amdgcn_mfma_f32_32x32x16_bf16(afl[rb], bfh[cb], acc[rb][cb], 0, 0, 0);
        }
    }
  }

#pragma unroll
  for (int rb = 0; rb < 2; ++rb) {
    int m_base = m0 + wm * 64 + rb * 32;
#pragma unroll
    for (int cb = 0; cb < 2; ++cb) {
      int n_g = n0 + wn * 64 + cb * 32 + l31;
#pragma unroll
      for (int reg = 0; reg < 16; ++reg) {
        int row = (reg & 3) + 8 * (reg >> 2) + 4 * g;
        out[(size_t)(m_base + row) * 512 + n_g] = acc[rb][cb][reg];
      }
    }
  }
}

// ---------------------------------------------------------------------------
extern "C" void kernel_launch(void* const* d_in, const int* in_sizes, int n_in,
                              void* d_out, int out_size, void* d_ws, size_t ws_size,
                              hipStream_t stream) {
  (void)in_sizes; (void)n_in;
  const float* x     = (const float*)d_in[0];
  const float* R     = (const float*)d_in[1];
  const float* gamma = (const float*)d_in[2];
  const float* beta  = (const float*)d_in[3];
  const float* Wqkv  = (const float*)d_in[4];
  const float* Wout  = (const float*)d_in[5];
  const float* av    = (const float*)d_in[6];
  const float* cv    = (const float*)d_in[7];
  float* out = (float*)d_out;

  const size_t EL  = (size_t)B_ * N_ * DIM_;     // 4,194,304 elements
  const size_t SZT = EL * sizeof(ushort_t);      // 8 MiB per bf16 tensor

  char* p = (char*)d_ws;
  ushort_t* wqh = (ushort_t*)p;                  p += (size_t)1536 * 512 * 2;
  ushort_t* wql = (ushort_t*)p;                  p += (size_t)1536 * 512 * 2;
  ushort_t* woh = (ushort_t*)p;                  p += (size_t)512 * 512 * 2;
  ushort_t* wol = (ushort_t*)p;                  p += (size_t)512 * 512 * 2;
  ushort_t* qhb = (ushort_t*)p;                  p += SZT;
  ushort_t* qlb = (ushort_t*)p;                  p += SZT;
  ushort_t* khb = (ushort_t*)p;                  p += SZT;
  ushort_t* klb = (ushort_t*)p;                  p += SZT;
  ushort_t* vtb = (ushort_t*)p;                  p += SZT;
  size_t base_need = (size_t)(p - (char*)d_ws);
  size_t needA = base_need + 2 * SZT;

  bool planA = (ws_size >= needA);
  // xn hi/lo doubles as aout hi/lo (xn dead after qkv_gemm).
  ushort_t* xnh = planA ? (ushort_t*)p : (ushort_t*)d_out;
  ushort_t* xnl = xnh + EL;
  float* gemm_dst = planA ? out : (float*)qhb;   // qh+ql region = 16.8 MB, dead by then

  transpose_split_kernel<<<dim3(24, 8), dim3(256), 0, stream>>>(Wqkv, wqh, wql, 512, 1536);
  transpose_split_kernel<<<dim3(8, 8), dim3(256), 0, stream>>>(Wout, woh, wol, 512, 512);
  ln_xn_kernel<<<dim3(2048), dim3(256), 0, stream>>>(x, gamma, beta, xnh, xnl);
  qkv_gemm_mfma<<<dim3(12, 64), dim3(256), 0, stream>>>(xnh, xnl, wqh, wql,
                                                        qhb, qlb, khb, klb, vtb);
  attn_mfma<<<dim3(32, 32), dim3(256), 0, stream>>>(qhb, qlb, khb, klb, vtb,
                                                    R, av, cv, xnh, xnl);
  out_gemm_mfma<<<dim3(4, 64), dim3(256), 0, stream>>>(xnh, xnl, woh, wol, gemm_dst);
  if (!planA) {
    hipMemcpyAsync(out, gemm_dst, (size_t)out_size * sizeof(float),
                   hipMemcpyDeviceToDevice, stream);
  }
}

// Round 7
// 371.430 us; speedup vs baseline: 2.1249x; 1.3323x over previous
//
#include <hip/hip_runtime.h>
#include <math.h>

#define B_   4
#define N_   2048
#define DIM_ 512
#define T_   16
#define H_   8
#define DH_  64
// num_patches = 128; 64-token tiles align within patches -> decay scalar per tile pair

typedef unsigned short ushort_t;
typedef __attribute__((ext_vector_type(8))) short bf16x8;    // 8 bf16 = 4 VGPRs
typedef __attribute__((ext_vector_type(16))) float f32x16;   // 32x32 MFMA acc

__device__ inline ushort_t bf16_rn(float x) {
  unsigned u = __builtin_bit_cast(unsigned, x);
  u += 0x7FFFu + ((u >> 16) & 1u);
  return (ushort_t)(u >> 16);
}
__device__ inline float bf16f(ushort_t h) {
  return __builtin_bit_cast(float, (unsigned)h << 16);
}
__device__ inline unsigned pack2(ushort_t a, ushort_t b) {
  return (unsigned)a | ((unsigned)b << 16);
}
__device__ inline void split2(float x, ushort_t &h, ushort_t &l) {
  h = bf16_rn(x);
  l = bf16_rn(x - bf16f(h));
}

// ---------------------------------------------------------------------------
// Kernel A: transpose + hi/lo split of a weight matrix.
// src [K][Nn] fp32 row-major  ->  dh/dl [Nn][K] bf16 hi/lo.
// ---------------------------------------------------------------------------
__global__ __launch_bounds__(256) void transpose_split_kernel(
    const float* __restrict__ src, ushort_t* __restrict__ dh,
    ushort_t* __restrict__ dl, int K, int Nn) {
  __shared__ float Ts[64][68];   // stride 68 floats: 16B-aligned rows, conflict-free
  int tid = threadIdx.x;
  int n0 = blockIdx.x * 64;
  int k0 = blockIdx.y * 64;
#pragma unroll
  for (int it = 0; it < 4; ++it) {
    int idx = tid + it * 256;          // 1024 float4s
    int r = idx >> 4, c4 = (idx & 15) * 4;
    *(float4*)&Ts[r][c4] = *(const float4*)&src[(size_t)(k0 + r) * Nn + n0 + c4];
  }
  __syncthreads();
#pragma unroll
  for (int it = 0; it < 2; ++it) {
    int idx = tid + it * 256;          // 512 output uint4s (per half)
    int n = idx >> 3, kc = (idx & 7) * 8;
    ushort_t hs[8], ls[8];
#pragma unroll
    for (int j = 0; j < 8; ++j) split2(Ts[kc + j][n], hs[j], ls[j]);
    uint4 uh, ul;
    uh.x = pack2(hs[0], hs[1]); uh.y = pack2(hs[2], hs[3]);
    uh.z = pack2(hs[4], hs[5]); uh.w = pack2(hs[6], hs[7]);
    ul.x = pack2(ls[0], ls[1]); ul.y = pack2(ls[2], ls[3]);
    ul.z = pack2(ls[4], ls[5]); ul.w = pack2(ls[6], ls[7]);
    size_t o = (size_t)(n0 + n) * K + k0 + kc;
    *(uint4*)&dh[o] = uh;
    *(uint4*)&dl[o] = ul;
  }
}

// ---------------------------------------------------------------------------
// Kernel B: LayerNorm -> xn hi/lo bf16 [8192][512]. One wave per row.
// ---------------------------------------------------------------------------
__global__ __launch_bounds__(256) void ln_xn_kernel(
    const float* __restrict__ x, const float* __restrict__ gamma,
    const float* __restrict__ beta, ushort_t* __restrict__ xnh,
    ushort_t* __restrict__ xnl) {
  int row  = blockIdx.x * 4 + (threadIdx.x >> 6);
  int lane = threadIdx.x & 63;
  const float4* xr = (const float4*)(x + (size_t)row * DIM_);
  float4 v0 = xr[lane * 2 + 0];
  float4 v1 = xr[lane * 2 + 1];
  float s  = v0.x + v0.y + v0.z + v0.w + v1.x + v1.y + v1.z + v1.w;
  float ss = v0.x*v0.x + v0.y*v0.y + v0.z*v0.z + v0.w*v0.w
           + v1.x*v1.x + v1.y*v1.y + v1.z*v1.z + v1.w*v1.w;
#pragma unroll
  for (int off = 32; off > 0; off >>= 1) {
    s  += __shfl_xor(s, off);
    ss += __shfl_xor(ss, off);
  }
  float mu  = s * (1.0f / DIM_);
  float var = ss * (1.0f / DIM_) - mu * mu;
  float rstd = rsqrtf(var + 1e-5f);
  float4 g0 = *(const float4*)&gamma[lane * 8];
  float4 g1 = *(const float4*)&gamma[lane * 8 + 4];
  float4 b0 = *(const float4*)&beta[lane * 8];
  float4 b1 = *(const float4*)&beta[lane * 8 + 4];
  float xv[8] = {v0.x, v0.y, v0.z, v0.w, v1.x, v1.y, v1.z, v1.w};
  float gv[8] = {g0.x, g0.y, g0.z, g0.w, g1.x, g1.y, g1.z, g1.w};
  float bv[8] = {b0.x, b0.y, b0.z, b0.w, b1.x, b1.y, b1.z, b1.w};
  ushort_t hs[8], ls[8];
#pragma unroll
  for (int j = 0; j < 8; ++j) {
    float xn = (xv[j] - mu) * rstd * gv[j] + bv[j];
    split2(xn, hs[j], ls[j]);
  }
  uint4 uh, ul;
  uh.x = pack2(hs[0], hs[1]); uh.y = pack2(hs[2], hs[3]);
  uh.z = pack2(hs[4], hs[5]); uh.w = pack2(hs[6], hs[7]);
  ul.x = pack2(ls[0], ls[1]); ul.y = pack2(ls[2], ls[3]);
  ul.z = pack2(ls[4], ls[5]); ul.w = pack2(ls[6], ls[7]);
  size_t o = (size_t)row * DIM_ + lane * 8;
  *(uint4*)&xnh[o] = uh;
  *(uint4*)&xnl[o] = ul;
}

// ---------------------------------------------------------------------------
// Kernel C: qkv = xn @ Wqkv^T, split-bf16 3-product MFMA (32x32x16).
// 128x128 tile, K-step 32, 4 waves in 2x2, each wave 64x64 (2x2 accs).
// Epilogue scatters q(hi/lo, x0.125), k(hi/lo) [bh][tok][d] and v^T [bh][d][tok].
// ---------------------------------------------------------------------------
__global__ __launch_bounds__(256, 2) void qkv_gemm_mfma(
    const ushort_t* __restrict__ xnh, const ushort_t* __restrict__ xnl,
    const ushort_t* __restrict__ wth, const ushort_t* __restrict__ wtl,
    ushort_t* __restrict__ qh, ushort_t* __restrict__ ql,
    ushort_t* __restrict__ kho, ushort_t* __restrict__ klo,
    ushort_t* __restrict__ vt) {
  __shared__ ushort_t Ah[128 * 40], Al[128 * 40], Bh[128 * 40], Bl[128 * 40];
  int tid = threadIdx.x;
  int w = tid >> 6, lane = tid & 63, l31 = lane & 31, g = lane >> 5;
  int wm = w >> 1, wn = w & 1;
  int n0 = blockIdx.x * 128;
  int m0 = blockIdx.y * 128;

  f32x16 acc[2][2];
#pragma unroll
  for (int i = 0; i < 2; ++i)
#pragma unroll
    for (int j = 0; j < 2; ++j)
#pragma unroll
      for (int e = 0; e < 16; ++e) acc[i][j][e] = 0.0f;

  int fm[2], fc[2];
#pragma unroll
  for (int it = 0; it < 2; ++it) {
    int f = tid + it * 256;
    fm[it] = f >> 2;
    fc[it] = (f & 3) * 8;
  }
  uint4 rah[2], ral[2], rbh[2], rbl[2];
#pragma unroll
  for (int it = 0; it < 2; ++it) {
    size_t ao = (size_t)(m0 + fm[it]) * 512 + fc[it];
    size_t bo = (size_t)(n0 + fm[it]) * 512 + fc[it];
    rah[it] = *(const uint4*)&xnh[ao];
    ral[it] = *(const uint4*)&xnl[ao];
    rbh[it] = *(const uint4*)&wth[bo];
    rbl[it] = *(const uint4*)&wtl[bo];
  }

  for (int kt = 0; kt < 16; ++kt) {
    __syncthreads();
#pragma unroll
    for (int it = 0; it < 2; ++it) {
      int o = fm[it] * 40 + fc[it];
      *(uint4*)&Ah[o] = rah[it];
      *(uint4*)&Al[o] = ral[it];
      *(uint4*)&Bh[o] = rbh[it];
      *(uint4*)&Bl[o] = rbl[it];
    }
    __syncthreads();
    int kn = (kt + 1 < 16) ? (kt + 1) * 32 : 0;
#pragma unroll
    for (int it = 0; it < 2; ++it) {
      size_t ao = (size_t)(m0 + fm[it]) * 512 + kn + fc[it];
      size_t bo = (size_t)(n0 + fm[it]) * 512 + kn + fc[it];
      rah[it] = *(const uint4*)&xnh[ao];
      ral[it] = *(const uint4*)&xnl[ao];
      rbh[it] = *(const uint4*)&wth[bo];
      rbl[it] = *(const uint4*)&wtl[bo];
    }
#pragma unroll
    for (int kc = 0; kc < 2; ++kc) {
      int off = kc * 16 + 8 * g;
      bf16x8 afh[2], afl[2], bfh[2], bfl[2];
#pragma unroll
      for (int rb = 0; rb < 2; ++rb) {
        int r = (wm * 64 + rb * 32 + l31) * 40 + off;
        afh[rb] = *(const bf16x8*)&Ah[r];
        afl[rb] = *(const bf16x8*)&Al[r];
      }
#pragma unroll
      for (int cb = 0; cb < 2; ++cb) {
        int r = (wn * 64 + cb * 32 + l31) * 40 + off;
        bfh[cb] = *(const bf16x8*)&Bh[r];
        bfl[cb] = *(const bf16x8*)&Bl[r];
      }
#pragma unroll
      for (int rb = 0; rb < 2; ++rb)
#pragma unroll
        for (int cb = 0; cb < 2; ++cb) {
          acc[rb][cb] = __builtin_amdgcn_mfma_f32_32x32x16_bf16(afh[rb], bfh[cb], acc[rb][cb], 0, 0, 0);
          acc[rb][cb] = __builtin_amdgcn_mfma_f32_32x32x16_bf16(afh[rb], bfl[cb], acc[rb][cb], 0, 0, 0);
          acc[rb][cb] = __builtin_amdgcn_mfma_f32_32x32x16_bf16(afl[rb], bfh[cb], acc[rb][cb], 0, 0, 0);
        }
    }
  }

  // epilogue: part uniform per block (n0: 0-383 q, 512.. k, 1024.. v)
  int part = n0 >> 9;
#pragma unroll
  for (int rb = 0; rb < 2; ++rb) {
    int m_base = m0 + wm * 64 + rb * 32;
#pragma unroll
    for (int cb = 0; cb < 2; ++cb) {
      int n_g = n0 + wn * 64 + cb * 32 + l31;
      int rem = n_g & 511, hh = rem >> 6, d = rem & 63;
      if (part == 2) {
#pragma unroll
        for (int grp = 0; grp < 4; ++grp) {
          int m_g = m_base + grp * 8 + 4 * g;
          int bb = m_g >> 11, tok = m_g & 2047;
          uint2 pk;
          pk.x = pack2(bf16_rn(acc[rb][cb][grp * 4 + 0]), bf16_rn(acc[rb][cb][grp * 4 + 1]));
          pk.y = pack2(bf16_rn(acc[rb][cb][grp * 4 + 2]), bf16_rn(acc[rb][cb][grp * 4 + 3]));
          *(uint2*)&vt[((size_t)(bb * 8 + hh) * 64 + d) * 2048 + tok] = pk;
        }
      } else {
        float sc = (part == 0) ? 0.125f : 1.0f;
        ushort_t* dsth = (part == 0) ? qh : kho;
        ushort_t* dstl = (part == 0) ? ql : klo;
#pragma unroll
        for (int reg = 0; reg < 16; ++reg) {
          int row = (reg & 3) + 8 * (reg >> 2) + 4 * g;
          int m_g = m_base + row;
          int bb = m_g >> 11, tok = m_g & 2047;
          ushort_t hi, lo;
          split2(acc[rb][cb][reg] * sc, hi, lo);
          size_t addr = ((size_t)(bb * 8 + hh) * 2048 + tok) * 64 + d;
          dsth[addr] = hi;
          dstl[addr] = lo;
        }
      }
    }
  }
}

// ---------------------------------------------------------------------------
// Kernel D: MFMA attention. grid x = bh (XCD affinity, R6: FETCH 194->64 MB),
// y = qt. Block = 64 queries x one (b,h), 4 waves.
// NO register prefetch and NO min-waves bound: R5/R6 showed the allocator
// spills long-lived prefetch regs to scratch (WRITE_SIZE 733/807 MB vs
// 16 MB legit; 30 ms first-touch scratch alloc). Loads are issued at the
// top of each staging step with immediate ds_write -- short VGPR lifetime.
// S = Qh*Kh + Qh*Kl + Ql*Kh; P,V bf16. No max-subtraction needed.
// LDS stride 72 shorts (conflict-free, R3/R5/R6: SQ_LDS_BANK_CONFLICT=0).
// ---------------------------------------------------------------------------
__global__ __launch_bounds__(256) void attn_mfma(
    const ushort_t* __restrict__ qh, const ushort_t* __restrict__ ql,
    const ushort_t* __restrict__ kho, const ushort_t* __restrict__ klo,
    const ushort_t* __restrict__ vt, const float* __restrict__ R,
    const float* __restrict__ a, const float* __restrict__ c,
    ushort_t* __restrict__ aoh, ushort_t* __restrict__ aol) {
  __shared__ ushort_t KhS[64 * 72], KlS[64 * 72], VtS[64 * 72], PS[64 * 72];
  __shared__ float rsLDS[2][64];

  int tid = threadIdx.x;
  int w = tid >> 6, lane = tid & 63, l31 = lane & 31, g = lane >> 5;
  int qhalf = w >> 1, khalf = w & 1;
  int bh = blockIdx.x;               // XCD-affinity swizzle
  int qt = blockIdx.y;
  int b = bh >> 3, h = bh & 7;
  float aab = fabsf(a[h]);
  float cab = fabsf(c[h]);

  // Q fragments straight from global (pre-scaled hi/lo)
  size_t qoff = ((size_t)bh * 2048 + qt * 64 + qhalf * 32 + l31) * 64;
  bf16x8 qfh[4], qfl[4];
#pragma unroll
  for (int d0i = 0; d0i < 4; ++d0i) {
    qfh[d0i] = *(const bf16x8*)&qh[qoff + d0i * 16 + 8 * g];
    qfl[d0i] = *(const bf16x8*)&ql[qoff + d0i * 16 + 8 * g];
  }

  int frow[2], fcc[2];
#pragma unroll
  for (int it = 0; it < 2; ++it) {
    int f = tid + it * 256;
    frow[it] = f >> 3;
    fcc[it] = (f & 7) * 8;
  }
  const ushort_t* kbase = kho + (size_t)bh * 2048 * 64;
  const ushort_t* lbase = klo + (size_t)bh * 2048 * 64;
  const ushort_t* vbase = vt + (size_t)bh * 64 * 2048;

  f32x16 oacc;
#pragma unroll
  for (int i = 0; i < 16; ++i) oacc[i] = 0.0f;
  float rs_acc[16] = {};
  int ti = qt >> 1;

#pragma unroll 1
  for (int kt = 0; kt < 32; ++kt) {
    __syncthreads();                      // prev iteration done reading LDS
    // ---- stage K/Kl/Vt: load -> immediate ds_write (short reg lifetime) ----
#pragma unroll
    for (int it = 0; it < 2; ++it) {
      uint4 tk = *(const uint4*)&kbase[(size_t)(kt * 64 + frow[it]) * 64 + fcc[it]];
      uint4 tl = *(const uint4*)&lbase[(size_t)(kt * 64 + frow[it]) * 64 + fcc[it]];
      uint4 tv = *(const uint4*)&vbase[(size_t)frow[it] * 2048 + kt * 64 + fcc[it]];
      int o = frow[it] * 72 + fcc[it];
      *(uint4*)&KhS[o] = tk;
      *(uint4*)&KlS[o] = tl;
      *(uint4*)&VtS[o] = tv;
    }
    __syncthreads();                      // staging visible

    // S = Q K^T (3-product split)
    f32x16 sacc;
#pragma unroll
    for (int i = 0; i < 16; ++i) sacc[i] = 0.0f;
    int krow = (khalf * 32 + l31) * 72;
#pragma unroll
    for (int d0i = 0; d0i < 4; ++d0i) {
      int off = krow + d0i * 16 + 8 * g;
      bf16x8 kfh = *(const bf16x8*)&KhS[off];
      bf16x8 kfl = *(const bf16x8*)&KlS[off];
      sacc = __builtin_amdgcn_mfma_f32_32x32x16_bf16(qfh[d0i], kfh, sacc, 0, 0, 0);
      sacc = __builtin_amdgcn_mfma_f32_32x32x16_bf16(qfh[d0i], kfl, sacc, 0, 0, 0);
      sacc = __builtin_amdgcn_mfma_f32_32x32x16_bf16(qfl[d0i], kfh, sacc, 0, 0, 0);
    }

    float Rv = R[b * (T_ * T_) + ti * T_ + (kt >> 1)];
    float dec = 1.0f / (1.0f + __expf(aab * Rv - cab));
#pragma unroll
    for (int reg = 0; reg < 16; ++reg) {
      float pv = __expf(fmaxf(sacc[reg], 0.0f) * dec);
      rs_acc[reg] += pv;
      int row = (reg & 3) + 8 * (reg >> 2) + 4 * g;
      PS[(qhalf * 32 + row) * 72 + khalf * 32 + l31] = bf16_rn(pv);
    }
    __syncthreads();                      // P visible to both k-half waves

#pragma unroll
    for (int k0i = 0; k0i < 4; ++k0i) {
      bf16x8 pf = *(const bf16x8*)&PS[(qhalf * 32 + l31) * 72 + k0i * 16 + 8 * g];
      bf16x8 vf = *(const bf16x8*)&VtS[(khalf * 32 + l31) * 72 + k0i * 16 + 8 * g];
      oacc = __builtin_amdgcn_mfma_f32_32x32x16_bf16(pf, vf, oacc, 0, 0, 0);
    }
  }

  // row-sum combine
#pragma unroll
  for (int reg = 0; reg < 16; ++reg) {
    float vsum = rs_acc[reg];
    vsum += __shfl_xor(vsum, 1);
    vsum += __shfl_xor(vsum, 2);
    vsum += __shfl_xor(vsum, 4);
    vsum += __shfl_xor(vsum, 8);
    vsum += __shfl_xor(vsum, 16);
    rs_acc[reg] = vsum;
  }
  if (l31 == 0) {
#pragma unroll
    for (int reg = 0; reg < 16; ++reg) {
      int row = (reg & 3) + 8 * (reg >> 2) + 4 * g;
      rsLDS[khalf][qhalf * 32 + row] = rs_acc[reg];
    }
  }
  __syncthreads();

  // normalize + write aout hi/lo [b][tok][h*64+d]
#pragma unroll
  for (int reg = 0; reg < 16; ++reg) {
    int row = (reg & 3) + 8 * (reg >> 2) + 4 * g;
    int qg = qhalf * 32 + row;
    float invs = 1.0f / (rsLDS[0][qg] + rsLDS[1][qg]);
    int tok = qt * 64 + qg;
    int d = khalf * 32 + l31;
    ushort_t hi, lo;
    split2(oacc[reg] * invs, hi, lo);
    size_t addr = ((size_t)b * 2048 + tok) * 512 + h * 64 + d;
    aoh[addr] = hi;
    aol[addr] = lo;
  }
}

// ---------------------------------------------------------------------------
// Kernel E: out = aout @ Wout^T, split-bf16 3-product MFMA. Same body as C.
// ---------------------------------------------------------------------------
__global__ __launch_bounds__(256, 2) void out_gemm_mfma(
    const ushort_t* __restrict__ ah, const ushort_t* __restrict__ al,
    const ushort_t* __restrict__ wth, const ushort_t* __restrict__ wtl,
    float* __restrict__ out) {
  __shared__ ushort_t Ah[128 * 40], Al[128 * 40], Bh[128 * 40], Bl[128 * 40];
  int tid = threadIdx.x;
  int w = tid >> 6, lane = tid & 63, l31 = lane & 31, g = lane >> 5;
  int wm = w >> 1, wn = w & 1;
  int n0 = blockIdx.x * 128;
  int m0 = blockIdx.y * 128;

  f32x16 acc[2][2];
#pragma unroll
  for (int i = 0; i < 2; ++i)
#pragma unroll
    for (int j = 0; j < 2; ++j)
#pragma unroll
      for (int e = 0; e < 16; ++e) acc[i][j][e] = 0.0f;

  int fm[2], fc[2];
#pragma unroll
  for (int it = 0; it < 2; ++it) {
    int f = tid + it * 256;
    fm[it] = f >> 2;
    fc[it] = (f & 3) * 8;
  }
  uint4 rah[2], ral[2], rbh[2], rbl[2];
#pragma unroll
  for (int it = 0; it < 2; ++it) {
    size_t ao = (size_t)(m0 + fm[it]) * 512 + fc[it];
    size_t bo = (size_t)(n0 + fm[it]) * 512 + fc[it];
    rah[it] = *(const uint4*)&ah[ao];
    ral[it] = *(const uint4*)&al[ao];
    rbh[it] = *(const uint4*)&wth[bo];
    rbl[it] = *(const uint4*)&wtl[bo];
  }

  for (int kt = 0; kt < 16; ++kt) {
    __syncthreads();
#pragma unroll
    for (int it = 0; it < 2; ++it) {
      int o = fm[it] * 40 + fc[it];
      *(uint4*)&Ah[o] = rah[it];
      *(uint4*)&Al[o] = ral[it];
      *(uint4*)&Bh[o] = rbh[it];
      *(uint4*)&Bl[o] = rbl[it];
    }
    __syncthreads();
    int kn = (kt + 1 < 16) ? (kt + 1) * 32 : 0;
#pragma unroll
    for (int it = 0; it < 2; ++it) {
      size_t ao = (size_t)(m0 + fm[it]) * 512 + kn + fc[it];
      size_t bo = (size_t)(n0 + fm[it]) * 512 + kn + fc[it];
      rah[it] = *(const uint4*)&ah[ao];
      ral[it] = *(const uint4*)&al[ao];
      rbh[it] = *(const uint4*)&wth[bo];
      rbl[it] = *(const uint4*)&wtl[bo];
    }
#pragma unroll
    for (int kc = 0; kc < 2; ++kc) {
      int off = kc * 16 + 8 * g;
      bf16x8 afh[2], afl[2], bfh[2], bfl[2];
#pragma unroll
      for (int rb = 0; rb < 2; ++rb) {
        int r = (wm * 64 + rb * 32 + l31) * 40 + off;
        afh[rb] = *(const bf16x8*)&Ah[r];
        afl[rb] = *(const bf16x8*)&Al[r];
      }
#pragma unroll
      for (int cb = 0; cb < 2; ++cb) {
        int r = (wn * 64 + cb * 32 + l31) * 40 + off;
        bfh[cb] = *(const bf16x8*)&Bh[r];
        bfl[cb] = *(const bf16x8*)&Bl[r];
      }
#pragma unroll
      for (int rb = 0; rb < 2; ++rb)
#pragma unroll
        for (int cb = 0; cb < 2; ++cb) {
          acc[rb][cb] = __builtin_amdgcn_mfma_f32_32x32x16_bf16(afh[rb], bfh[cb], acc[rb][cb], 0, 0, 0);
          acc[rb][cb] = __builtin_amdgcn_mfma_f32_32x32x16_bf16(afh[rb], bfl[cb], acc[rb][cb], 0, 0, 0);
          acc[rb][cb] = __builtin_amdgcn_mfma_f32_32x32x16_bf16(afl[rb], bfh[cb], acc[rb][cb], 0, 0, 0);
        }
    }
  }

#pragma unroll
  for (int rb = 0; rb < 2; ++rb) {
    int m_base = m0 + wm * 64 + rb * 32;
#pragma unroll
    for (int cb = 0; cb < 2; ++cb) {
      int n_g = n0 + wn * 64 + cb * 32 + l31;
#pragma unroll
      for (int reg = 0; reg < 16; ++reg) {
        int row = (reg & 3) + 8 * (reg >> 2) + 4 * g;
        out[(size_t)(m_base + row) * 512 + n_g] = acc[rb][cb][reg];
      }
    }
  }
}

// ---------------------------------------------------------------------------
extern "C" void kernel_launch(void* const* d_in, const int* in_sizes, int n_in,
                              void* d_out, int out_size, void* d_ws, size_t ws_size,
                              hipStream_t stream) {
  (void)in_sizes; (void)n_in;
  const float* x     = (const float*)d_in[0];
  const float* R     = (const float*)d_in[1];
  const float* gamma = (const float*)d_in[2];
  const float* beta  = (const float*)d_in[3];
  const float* Wqkv  = (const float*)d_in[4];
  const float* Wout  = (const float*)d_in[5];
  const float* av    = (const float*)d_in[6];
  const float* cv    = (const float*)d_in[7];
  float* out = (float*)d_out;

  const size_t EL  = (size_t)B_ * N_ * DIM_;     // 4,194,304 elements
  const size_t SZT = EL * sizeof(ushort_t);      // 8 MiB per bf16 tensor

  char* p = (char*)d_ws;
  ushort_t* wqh = (ushort_t*)p;                  p += (size_t)1536 * 512 * 2;
  ushort_t* wql = (ushort_t*)p;                  p += (size_t)1536 * 512 * 2;
  ushort_t* woh = (ushort_t*)p;                  p += (size_t)512 * 512 * 2;
  ushort_t* wol = (ushort_t*)p;                  p += (size_t)512 * 512 * 2;
  ushort_t* qhb = (ushort_t*)p;                  p += SZT;
  ushort_t* qlb = (ushort_t*)p;                  p += SZT;
  ushort_t* khb = (ushort_t*)p;                  p += SZT;
  ushort_t* klb = (ushort_t*)p;                  p += SZT;
  ushort_t* vtb = (ushort_t*)p;                  p += SZT;
  size_t base_need = (size_t)(p - (char*)d_ws);
  size_t needA = base_need + 2 * SZT;

  bool planA = (ws_size >= needA);
  // xn hi/lo doubles as aout hi/lo (xn dead after qkv_gemm).
  ushort_t* xnh = planA ? (ushort_t*)p : (ushort_t*)d_out;
  ushort_t* xnl = xnh + EL;
  float* gemm_dst = planA ? out : (float*)qhb;   // qh+ql region = 16.8 MB, dead by then

  transpose_split_kernel<<<dim3(24, 8), dim3(256), 0, stream>>>(Wqkv, wqh, wql, 512, 1536);
  transpose_split_kernel<<<dim3(8, 8), dim3(256), 0, stream>>>(Wout, woh, wol, 512, 512);
  ln_xn_kernel<<<dim3(2048), dim3(256), 0, stream>>>(x, gamma, beta, xnh, xnl);
  qkv_gemm_mfma<<<dim3(12, 64), dim3(256), 0, stream>>>(xnh, xnl, wqh, wql,
                                                        qhb, qlb, khb, klb, vtb);
  attn_mfma<<<dim3(32, 32), dim3(256), 0, stream>>>(qhb, qlb, khb, klb, vtb,
                                                    R, av, cv, xnh, xnl);
  out_gemm_mfma<<<dim3(4, 64), dim3(256), 0, stream>>>(xnh, xnl, woh, wol, gemm_dst);
  if (!planA) {
    hipMemcpyAsync(out, gemm_dst, (size_t)out_size * sizeof(float),
                   hipMemcpyDeviceToDevice, stream);
  }
}

// Round 8
// 263.661 us; speedup vs baseline: 2.9935x; 1.4087x over previous
//
#include <hip/hip_runtime.h>
#include <math.h>

#define B_   4
#define N_   2048
#define DIM_ 512
#define T_   16
#define H_   8
#define DH_  64
// num_patches = 128; 64-token tiles align within patches -> decay scalar per tile pair

typedef unsigned short ushort_t;
typedef __attribute__((ext_vector_type(8))) short bf16x8;    // 8 bf16 = 4 VGPRs
typedef __attribute__((ext_vector_type(16))) float f32x16;   // 32x32 MFMA acc

__device__ inline ushort_t bf16_rn(float x) {
  unsigned u = __builtin_bit_cast(unsigned, x);
  u += 0x7FFFu + ((u >> 16) & 1u);
  return (ushort_t)(u >> 16);
}
__device__ inline float bf16f(ushort_t h) {
  return __builtin_bit_cast(float, (unsigned)h << 16);
}
__device__ inline unsigned pack2(ushort_t a, ushort_t b) {
  return (unsigned)a | ((unsigned)b << 16);
}
__device__ inline void split2(float x, ushort_t &h, ushort_t &l) {
  h = bf16_rn(x);
  l = bf16_rn(x - bf16f(h));
}

// ---------------------------------------------------------------------------
// Kernel A: transpose + hi/lo split of a weight matrix.
// src [K][Nn] fp32 row-major  ->  dh/dl [Nn][K] bf16 hi/lo.
// ---------------------------------------------------------------------------
__global__ __launch_bounds__(256) void transpose_split_kernel(
    const float* __restrict__ src, ushort_t* __restrict__ dh,
    ushort_t* __restrict__ dl, int K, int Nn) {
  __shared__ float Ts[64][68];   // stride 68 floats: 16B-aligned rows, conflict-free
  int tid = threadIdx.x;
  int n0 = blockIdx.x * 64;
  int k0 = blockIdx.y * 64;
#pragma unroll
  for (int it = 0; it < 4; ++it) {
    int idx = tid + it * 256;          // 1024 float4s
    int r = idx >> 4, c4 = (idx & 15) * 4;
    *(float4*)&Ts[r][c4] = *(const float4*)&src[(size_t)(k0 + r) * Nn + n0 + c4];
  }
  __syncthreads();
#pragma unroll
  for (int it = 0; it < 2; ++it) {
    int idx = tid + it * 256;          // 512 output uint4s (per half)
    int n = idx >> 3, kc = (idx & 7) * 8;
    ushort_t hs[8], ls[8];
#pragma unroll
    for (int j = 0; j < 8; ++j) split2(Ts[kc + j][n], hs[j], ls[j]);
    uint4 uh, ul;
    uh.x = pack2(hs[0], hs[1]); uh.y = pack2(hs[2], hs[3]);
    uh.z = pack2(hs[4], hs[5]); uh.w = pack2(hs[6], hs[7]);
    ul.x = pack2(ls[0], ls[1]); ul.y = pack2(ls[2], ls[3]);
    ul.z = pack2(ls[4], ls[5]); ul.w = pack2(ls[6], ls[7]);
    size_t o = (size_t)(n0 + n) * K + k0 + kc;
    *(uint4*)&dh[o] = uh;
    *(uint4*)&dl[o] = ul;
  }
}

// ---------------------------------------------------------------------------
// Kernel B: LayerNorm -> xn hi/lo bf16 [8192][512]. One wave per row.
// ---------------------------------------------------------------------------
__global__ __launch_bounds__(256) void ln_xn_kernel(
    const float* __restrict__ x, const float* __restrict__ gamma,
    const float* __restrict__ beta, ushort_t* __restrict__ xnh,
    ushort_t* __restrict__ xnl) {
  int row  = blockIdx.x * 4 + (threadIdx.x >> 6);
  int lane = threadIdx.x & 63;
  const float4* xr = (const float4*)(x + (size_t)row * DIM_);
  float4 v0 = xr[lane * 2 + 0];
  float4 v1 = xr[lane * 2 + 1];
  float s  = v0.x + v0.y + v0.z + v0.w + v1.x + v1.y + v1.z + v1.w;
  float ss = v0.x*v0.x + v0.y*v0.y + v0.z*v0.z + v0.w*v0.w
           + v1.x*v1.x + v1.y*v1.y + v1.z*v1.z + v1.w*v1.w;
#pragma unroll
  for (int off = 32; off > 0; off >>= 1) {
    s  += __shfl_xor(s, off);
    ss += __shfl_xor(ss, off);
  }
  float mu  = s * (1.0f / DIM_);
  float var = ss * (1.0f / DIM_) - mu * mu;
  float rstd = rsqrtf(var + 1e-5f);
  float4 g0 = *(const float4*)&gamma[lane * 8];
  float4 g1 = *(const float4*)&gamma[lane * 8 + 4];
  float4 b0 = *(const float4*)&beta[lane * 8];
  float4 b1 = *(const float4*)&beta[lane * 8 + 4];
  float xv[8] = {v0.x, v0.y, v0.z, v0.w, v1.x, v1.y, v1.z, v1.w};
  float gv[8] = {g0.x, g0.y, g0.z, g0.w, g1.x, g1.y, g1.z, g1.w};
  float bv[8] = {b0.x, b0.y, b0.z, b0.w, b1.x, b1.y, b1.z, b1.w};
  ushort_t hs[8], ls[8];
#pragma unroll
  for (int j = 0; j < 8; ++j) {
    float xn = (xv[j] - mu) * rstd * gv[j] + bv[j];
    split2(xn, hs[j], ls[j]);
  }
  uint4 uh, ul;
  uh.x = pack2(hs[0], hs[1]); uh.y = pack2(hs[2], hs[3]);
  uh.z = pack2(hs[4], hs[5]); uh.w = pack2(hs[6], hs[7]);
  ul.x = pack2(ls[0], ls[1]); ul.y = pack2(ls[2], ls[3]);
  ul.z = pack2(ls[4], ls[5]); ul.w = pack2(ls[6], ls[7]);
  size_t o = (size_t)row * DIM_ + lane * 8;
  *(uint4*)&xnh[o] = uh;
  *(uint4*)&xnl[o] = ul;
}

// ---------------------------------------------------------------------------
// Kernel C: qkv = xn @ Wqkv^T, split-bf16 3-product MFMA (32x32x16).
// 128x128 tile, K-step 32, 4 waves in 2x2, each wave 64x64 (2x2 accs).
// NO register prefetch / NO min-waves bound (R5-R7 lesson: long-lived
// prefetch regs spill to scratch -> WRITE_SIZE 380 MB vs 40 MB legit).
// Loads issue at the top of staging with immediate ds_write.
// Epilogue scatters q(hi/lo, x0.125), k(hi/lo) [bh][tok][d], v^T [bh][d][tok].
// ---------------------------------------------------------------------------
__global__ __launch_bounds__(256) void qkv_gemm_mfma(
    const ushort_t* __restrict__ xnh, const ushort_t* __restrict__ xnl,
    const ushort_t* __restrict__ wth, const ushort_t* __restrict__ wtl,
    ushort_t* __restrict__ qh, ushort_t* __restrict__ ql,
    ushort_t* __restrict__ kho, ushort_t* __restrict__ klo,
    ushort_t* __restrict__ vt) {
  __shared__ ushort_t Ah[128 * 40], Al[128 * 40], Bh[128 * 40], Bl[128 * 40];
  int tid = threadIdx.x;
  int w = tid >> 6, lane = tid & 63, l31 = lane & 31, g = lane >> 5;
  int wm = w >> 1, wn = w & 1;
  int n0 = blockIdx.x * 128;
  int m0 = blockIdx.y * 128;

  f32x16 acc[2][2];
#pragma unroll
  for (int i = 0; i < 2; ++i)
#pragma unroll
    for (int j = 0; j < 2; ++j)
#pragma unroll
      for (int e = 0; e < 16; ++e) acc[i][j][e] = 0.0f;

  int fm[2], fc[2];
#pragma unroll
  for (int it = 0; it < 2; ++it) {
    int f = tid + it * 256;
    fm[it] = f >> 2;
    fc[it] = (f & 3) * 8;
  }

#pragma unroll 1
  for (int kt = 0; kt < 16; ++kt) {
    __syncthreads();
    // stage: load -> immediate ds_write (short VGPR lifetime, no spills)
#pragma unroll
    for (int it = 0; it < 2; ++it) {
      size_t ao = (size_t)(m0 + fm[it]) * 512 + kt * 32 + fc[it];
      size_t bo = (size_t)(n0 + fm[it]) * 512 + kt * 32 + fc[it];
      uint4 tah = *(const uint4*)&xnh[ao];
      uint4 tal = *(const uint4*)&xnl[ao];
      uint4 tbh = *(const uint4*)&wth[bo];
      uint4 tbl = *(const uint4*)&wtl[bo];
      int o = fm[it] * 40 + fc[it];
      *(uint4*)&Ah[o] = tah;
      *(uint4*)&Al[o] = tal;
      *(uint4*)&Bh[o] = tbh;
      *(uint4*)&Bl[o] = tbl;
    }
    __syncthreads();
#pragma unroll
    for (int kc = 0; kc < 2; ++kc) {
      int off = kc * 16 + 8 * g;
      bf16x8 afh[2], afl[2], bfh[2], bfl[2];
#pragma unroll
      for (int rb = 0; rb < 2; ++rb) {
        int r = (wm * 64 + rb * 32 + l31) * 40 + off;
        afh[rb] = *(const bf16x8*)&Ah[r];
        afl[rb] = *(const bf16x8*)&Al[r];
      }
#pragma unroll
      for (int cb = 0; cb < 2; ++cb) {
        int r = (wn * 64 + cb * 32 + l31) * 40 + off;
        bfh[cb] = *(const bf16x8*)&Bh[r];
        bfl[cb] = *(const bf16x8*)&Bl[r];
      }
#pragma unroll
      for (int rb = 0; rb < 2; ++rb)
#pragma unroll
        for (int cb = 0; cb < 2; ++cb) {
          acc[rb][cb] = __builtin_amdgcn_mfma_f32_32x32x16_bf16(afh[rb], bfh[cb], acc[rb][cb], 0, 0, 0);
          acc[rb][cb] = __builtin_amdgcn_mfma_f32_32x32x16_bf16(afh[rb], bfl[cb], acc[rb][cb], 0, 0, 0);
          acc[rb][cb] = __builtin_amdgcn_mfma_f32_32x32x16_bf16(afl[rb], bfh[cb], acc[rb][cb], 0, 0, 0);
        }
    }
  }

  // epilogue: part uniform per block (n0: 0-383 q, 512.. k, 1024.. v)
  int part = n0 >> 9;
#pragma unroll
  for (int rb = 0; rb < 2; ++rb) {
    int m_base = m0 + wm * 64 + rb * 32;
#pragma unroll
    for (int cb = 0; cb < 2; ++cb) {
      int n_g = n0 + wn * 64 + cb * 32 + l31;
      int rem = n_g & 511, hh = rem >> 6, d = rem & 63;
      if (part == 2) {
#pragma unroll
        for (int grp = 0; grp < 4; ++grp) {
          int m_g = m_base + grp * 8 + 4 * g;
          int bb = m_g >> 11, tok = m_g & 2047;
          uint2 pk;
          pk.x = pack2(bf16_rn(acc[rb][cb][grp * 4 + 0]), bf16_rn(acc[rb][cb][grp * 4 + 1]));
          pk.y = pack2(bf16_rn(acc[rb][cb][grp * 4 + 2]), bf16_rn(acc[rb][cb][grp * 4 + 3]));
          *(uint2*)&vt[((size_t)(bb * 8 + hh) * 64 + d) * 2048 + tok] = pk;
        }
      } else {
        float sc = (part == 0) ? 0.125f : 1.0f;
        ushort_t* dsth = (part == 0) ? qh : kho;
        ushort_t* dstl = (part == 0) ? ql : klo;
#pragma unroll
        for (int reg = 0; reg < 16; ++reg) {
          int row = (reg & 3) + 8 * (reg >> 2) + 4 * g;
          int m_g = m_base + row;
          int bb = m_g >> 11, tok = m_g & 2047;
          ushort_t hi, lo;
          split2(acc[rb][cb][reg] * sc, hi, lo);
          size_t addr = ((size_t)(bb * 8 + hh) * 2048 + tok) * 64 + d;
          dsth[addr] = hi;
          dstl[addr] = lo;
        }
      }
    }
  }
}

// ---------------------------------------------------------------------------
// Kernel D: MFMA attention. grid x = bh (XCD affinity, R6: FETCH 194->64 MB),
// y = qt. Block = 64 queries x one (b,h), 4 waves. No prefetch / no bound
// (R7: spill-free, WRITE back to ~16 MB, dropped out of top-5).
// S = Qh*Kh + Qh*Kl + Ql*Kh; P,V bf16. No max-subtraction needed.
// LDS stride 72 shorts (conflict-free, measured 0 conflicts R3-R7).
// ---------------------------------------------------------------------------
__global__ __launch_bounds__(256) void attn_mfma(
    const ushort_t* __restrict__ qh, const ushort_t* __restrict__ ql,
    const ushort_t* __restrict__ kho, const ushort_t* __restrict__ klo,
    const ushort_t* __restrict__ vt, const float* __restrict__ R,
    const float* __restrict__ a, const float* __restrict__ c,
    ushort_t* __restrict__ aoh, ushort_t* __restrict__ aol) {
  __shared__ ushort_t KhS[64 * 72], KlS[64 * 72], VtS[64 * 72], PS[64 * 72];
  __shared__ float rsLDS[2][64];

  int tid = threadIdx.x;
  int w = tid >> 6, lane = tid & 63, l31 = lane & 31, g = lane >> 5;
  int qhalf = w >> 1, khalf = w & 1;
  int bh = blockIdx.x;               // XCD-affinity swizzle
  int qt = blockIdx.y;
  int b = bh >> 3, h = bh & 7;
  float aab = fabsf(a[h]);
  float cab = fabsf(c[h]);

  // Q fragments straight from global (pre-scaled hi/lo)
  size_t qoff = ((size_t)bh * 2048 + qt * 64 + qhalf * 32 + l31) * 64;
  bf16x8 qfh[4], qfl[4];
#pragma unroll
  for (int d0i = 0; d0i < 4; ++d0i) {
    qfh[d0i] = *(const bf16x8*)&qh[qoff + d0i * 16 + 8 * g];
    qfl[d0i] = *(const bf16x8*)&ql[qoff + d0i * 16 + 8 * g];
  }

  int frow[2], fcc[2];
#pragma unroll
  for (int it = 0; it < 2; ++it) {
    int f = tid + it * 256;
    frow[it] = f >> 3;
    fcc[it] = (f & 7) * 8;
  }
  const ushort_t* kbase = kho + (size_t)bh * 2048 * 64;
  const ushort_t* lbase = klo + (size_t)bh * 2048 * 64;
  const ushort_t* vbase = vt + (size_t)bh * 64 * 2048;

  f32x16 oacc;
#pragma unroll
  for (int i = 0; i < 16; ++i) oacc[i] = 0.0f;
  float rs_acc[16] = {};
  int ti = qt >> 1;

#pragma unroll 1
  for (int kt = 0; kt < 32; ++kt) {
    __syncthreads();                      // prev iteration done reading LDS
#pragma unroll
    for (int it = 0; it < 2; ++it) {
      uint4 tk = *(const uint4*)&kbase[(size_t)(kt * 64 + frow[it]) * 64 + fcc[it]];
      uint4 tl = *(const uint4*)&lbase[(size_t)(kt * 64 + frow[it]) * 64 + fcc[it]];
      uint4 tv = *(const uint4*)&vbase[(size_t)frow[it] * 2048 + kt * 64 + fcc[it]];
      int o = frow[it] * 72 + fcc[it];
      *(uint4*)&KhS[o] = tk;
      *(uint4*)&KlS[o] = tl;
      *(uint4*)&VtS[o] = tv;
    }
    __syncthreads();                      // staging visible

    // S = Q K^T (3-product split)
    f32x16 sacc;
#pragma unroll
    for (int i = 0; i < 16; ++i) sacc[i] = 0.0f;
    int krow = (khalf * 32 + l31) * 72;
#pragma unroll
    for (int d0i = 0; d0i < 4; ++d0i) {
      int off = krow + d0i * 16 + 8 * g;
      bf16x8 kfh = *(const bf16x8*)&KhS[off];
      bf16x8 kfl = *(const bf16x8*)&KlS[off];
      sacc = __builtin_amdgcn_mfma_f32_32x32x16_bf16(qfh[d0i], kfh, sacc, 0, 0, 0);
      sacc = __builtin_amdgcn_mfma_f32_32x32x16_bf16(qfh[d0i], kfl, sacc, 0, 0, 0);
      sacc = __builtin_amdgcn_mfma_f32_32x32x16_bf16(qfl[d0i], kfh, sacc, 0, 0, 0);
    }

    float Rv = R[b * (T_ * T_) + ti * T_ + (kt >> 1)];
    float dec = 1.0f / (1.0f + __expf(aab * Rv - cab));
#pragma unroll
    for (int reg = 0; reg < 16; ++reg) {
      float pv = __expf(fmaxf(sacc[reg], 0.0f) * dec);
      rs_acc[reg] += pv;
      int row = (reg & 3) + 8 * (reg >> 2) + 4 * g;
      PS[(qhalf * 32 + row) * 72 + khalf * 32 + l31] = bf16_rn(pv);
    }
    __syncthreads();                      // P visible to both k-half waves

#pragma unroll
    for (int k0i = 0; k0i < 4; ++k0i) {
      bf16x8 pf = *(const bf16x8*)&PS[(qhalf * 32 + l31) * 72 + k0i * 16 + 8 * g];
      bf16x8 vf = *(const bf16x8*)&VtS[(khalf * 32 + l31) * 72 + k0i * 16 + 8 * g];
      oacc = __builtin_amdgcn_mfma_f32_32x32x16_bf16(pf, vf, oacc, 0, 0, 0);
    }
  }

  // row-sum combine
#pragma unroll
  for (int reg = 0; reg < 16; ++reg) {
    float vsum = rs_acc[reg];
    vsum += __shfl_xor(vsum, 1);
    vsum += __shfl_xor(vsum, 2);
    vsum += __shfl_xor(vsum, 4);
    vsum += __shfl_xor(vsum, 8);
    vsum += __shfl_xor(vsum, 16);
    rs_acc[reg] = vsum;
  }
  if (l31 == 0) {
#pragma unroll
    for (int reg = 0; reg < 16; ++reg) {
      int row = (reg & 3) + 8 * (reg >> 2) + 4 * g;
      rsLDS[khalf][qhalf * 32 + row] = rs_acc[reg];
    }
  }
  __syncthreads();

  // normalize + write aout hi/lo [b][tok][h*64+d]
#pragma unroll
  for (int reg = 0; reg < 16; ++reg) {
    int row = (reg & 3) + 8 * (reg >> 2) + 4 * g;
    int qg = qhalf * 32 + row;
    float invs = 1.0f / (rsLDS[0][qg] + rsLDS[1][qg]);
    int tok = qt * 64 + qg;
    int d = khalf * 32 + l31;
    ushort_t hi, lo;
    split2(oacc[reg] * invs, hi, lo);
    size_t addr = ((size_t)b * 2048 + tok) * 512 + h * 64 + d;
    aoh[addr] = hi;
    aol[addr] = lo;
  }
}

// ---------------------------------------------------------------------------
// Kernel E: out = aout @ Wout^T. Same structure as C (no prefetch, no bound).
// ---------------------------------------------------------------------------
__global__ __launch_bounds__(256) void out_gemm_mfma(
    const ushort_t* __restrict__ ah, const ushort_t* __restrict__ al,
    const ushort_t* __restrict__ wth, const ushort_t* __restrict__ wtl,
    float* __restrict__ out) {
  __shared__ ushort_t Ah[128 * 40], Al[128 * 40], Bh[128 * 40], Bl[128 * 40];
  int tid = threadIdx.x;
  int w = tid >> 6, lane = tid & 63, l31 = lane & 31, g = lane >> 5;
  int wm = w >> 1, wn = w & 1;
  int n0 = blockIdx.x * 128;
  int m0 = blockIdx.y * 128;

  f32x16 acc[2][2];
#pragma unroll
  for (int i = 0; i < 2; ++i)
#pragma unroll
    for (int j = 0; j < 2; ++j)
#pragma unroll
      for (int e = 0; e < 16; ++e) acc[i][j][e] = 0.0f;

  int fm[2], fc[2];
#pragma unroll
  for (int it = 0; it < 2; ++it) {
    int f = tid + it * 256;
    fm[it] = f >> 2;
    fc[it] = (f & 3) * 8;
  }

#pragma unroll 1
  for (int kt = 0; kt < 16; ++kt) {
    __syncthreads();
#pragma unroll
    for (int it = 0; it < 2; ++it) {
      size_t ao = (size_t)(m0 + fm[it]) * 512 + kt * 32 + fc[it];
      size_t bo = (size_t)(n0 + fm[it]) * 512 + kt * 32 + fc[it];
      uint4 tah = *(const uint4*)&ah[ao];
      uint4 tal = *(const uint4*)&al[ao];
      uint4 tbh = *(const uint4*)&wth[bo];
      uint4 tbl = *(const uint4*)&wtl[bo];
      int o = fm[it] * 40 + fc[it];
      *(uint4*)&Ah[o] = tah;
      *(uint4*)&Al[o] = tal;
      *(uint4*)&Bh[o] = tbh;
      *(uint4*)&Bl[o] = tbl;
    }
    __syncthreads();
#pragma unroll
    for (int kc = 0; kc < 2; ++kc) {
      int off = kc * 16 + 8 * g;
      bf16x8 afh[2], afl[2], bfh[2], bfl[2];
#pragma unroll
      for (int rb = 0; rb < 2; ++rb) {
        int r = (wm * 64 + rb * 32 + l31) * 40 + off;
        afh[rb] = *(const bf16x8*)&Ah[r];
        afl[rb] = *(const bf16x8*)&Al[r];
      }
#pragma unroll
      for (int cb = 0; cb < 2; ++cb) {
        int r = (wn * 64 + cb * 32 + l31) * 40 + off;
        bfh[cb] = *(const bf16x8*)&Bh[r];
        bfl[cb] = *(const bf16x8*)&Bl[r];
      }
#pragma unroll
      for (int rb = 0; rb < 2; ++rb)
#pragma unroll
        for (int cb = 0; cb < 2; ++cb) {
          acc[rb][cb] = __builtin_amdgcn_mfma_f32_32x32x16_bf16(afh[rb], bfh[cb], acc[rb][cb], 0, 0, 0);
          acc[rb][cb] = __builtin_amdgcn_mfma_f32_32x32x16_bf16(afh[rb], bfl[cb], acc[rb][cb], 0, 0, 0);
          acc[rb][cb] = __builtin_amdgcn_mfma_f32_32x32x16_bf16(afl[rb], bfh[cb], acc[rb][cb], 0, 0, 0);
        }
    }
  }

#pragma unroll
  for (int rb = 0; rb < 2; ++rb) {
    int m_base = m0 + wm * 64 + rb * 32;
#pragma unroll
    for (int cb = 0; cb < 2; ++cb) {
      int n_g = n0 + wn * 64 + cb * 32 + l31;
#pragma unroll
      for (int reg = 0; reg < 16; ++reg) {
        int row = (reg & 3) + 8 * (reg >> 2) + 4 * g;
        out[(size_t)(m_base + row) * 512 + n_g] = acc[rb][cb][reg];
      }
    }
  }
}

// ---------------------------------------------------------------------------
extern "C" void kernel_launch(void* const* d_in, const int* in_sizes, int n_in,
                              void* d_out, int out_size, void* d_ws, size_t ws_size,
                              hipStream_t stream) {
  (void)in_sizes; (void)n_in;
  const float* x     = (const float*)d_in[0];
  const float* R     = (const float*)d_in[1];
  const float* gamma = (const float*)d_in[2];
  const float* beta  = (const float*)d_in[3];
  const float* Wqkv  = (const float*)d_in[4];
  const float* Wout  = (const float*)d_in[5];
  const float* av    = (const float*)d_in[6];
  const float* cv    = (const float*)d_in[7];
  float* out = (float*)d_out;

  const size_t EL  = (size_t)B_ * N_ * DIM_;     // 4,194,304 elements
  const size_t SZT = EL * sizeof(ushort_t);      // 8 MiB per bf16 tensor

  char* p = (char*)d_ws;
  ushort_t* wqh = (ushort_t*)p;                  p += (size_t)1536 * 512 * 2;
  ushort_t* wql = (ushort_t*)p;                  p += (size_t)1536 * 512 * 2;
  ushort_t* woh = (ushort_t*)p;                  p += (size_t)512 * 512 * 2;
  ushort_t* wol = (ushort_t*)p;                  p += (size_t)512 * 512 * 2;
  ushort_t* qhb = (ushort_t*)p;                  p += SZT;
  ushort_t* qlb = (ushort_t*)p;                  p += SZT;
  ushort_t* khb = (ushort_t*)p;                  p += SZT;
  ushort_t* klb = (ushort_t*)p;                  p += SZT;
  ushort_t* vtb = (ushort_t*)p;                  p += SZT;
  size_t base_need = (size_t)(p - (char*)d_ws);
  size_t needA = base_need + 2 * SZT;

  bool planA = (ws_size >= needA);
  // xn hi/lo doubles as aout hi/lo (xn dead after qkv_gemm).
  ushort_t* xnh = planA ? (ushort_t*)p : (ushort_t*)d_out;
  ushort_t* xnl = xnh + EL;
  float* gemm_dst = planA ? out : (float*)qhb;   // qh+ql region = 16.8 MB, dead by then

  transpose_split_kernel<<<dim3(24, 8), dim3(256), 0, stream>>>(Wqkv, wqh, wql, 512, 1536);
  transpose_split_kernel<<<dim3(8, 8), dim3(256), 0, stream>>>(Wout, woh, wol, 512, 512);
  ln_xn_kernel<<<dim3(2048), dim3(256), 0, stream>>>(x, gamma, beta, xnh, xnl);
  qkv_gemm_mfma<<<dim3(12, 64), dim3(256), 0, stream>>>(xnh, xnl, wqh, wql,
                                                        qhb, qlb, khb, klb, vtb);
  attn_mfma<<<dim3(32, 32), dim3(256), 0, stream>>>(qhb, qlb, khb, klb, vtb,
                                                    R, av, cv, xnh, xnl);
  out_gemm_mfma<<<dim3(4, 64), dim3(256), 0, stream>>>(xnh, xnl, woh, wol, gemm_dst);
  if (!planA) {
    hipMemcpyAsync(out, gemm_dst, (size_t)out_size * sizeof(float),
                   hipMemcpyDeviceToDevice, stream);
  }
}